// Round 11
// baseline (1324.277 us; speedup 1.0000x reference)
//
#include <hip/hip_runtime.h>
#include <hip/hip_bf16.h>
#include <math.h>

// ---- problem constants ----
#define BATCH   8
#define C_IN    3
#define IMG_SZ  224
#define P_SZ    16
#define NPATCH  196                 // (224/16)^2
#define MSEQ    197                 // NPATCH + cls
#define DDIM    192
#define EDIM    384
#define NSTATE  16
#define ENDIM   (EDIM*NSTATE)       // 6144
#define LLAYERS 2
#define ROWS    (BATCH*MSEQ)        // 1576
#define PROWS   (BATCH*NPATCH)      // 1568
#define PATCH_K (C_IN*P_SZ*P_SZ)    // 768

// precise silu (enters the scan only linearly)
__device__ __forceinline__ float silu_f(float x) { return x / (1.f + expf(-x)); }

// ------------------------------------------------------------------
// patchify: img (B,3,224,224) -> patches (PROWS, 768)
// ------------------------------------------------------------------
__global__ __launch_bounds__(256) void patchify_k(const float* __restrict__ img,
                                                  float* __restrict__ out) {
    int idx = blockIdx.x * 256 + threadIdx.x;
    if (idx >= PROWS * PATCH_K) return;
    int r = idx / PATCH_K, col = idx - r * PATCH_K;
    int b = r / NPATCH, p = r - b * NPATCH;
    int ph = p / 14, pw = p - ph * 14;
    int c = col >> 8, rem = col & 255, py = rem >> 4, px = rem & 15;
    out[idx] = img[((b * C_IN + c) * IMG_SZ + ph * P_SZ + py) * IMG_SZ + pw * P_SZ + px];
}

// ------------------------------------------------------------------
// assemble x = concat(cls, xemb) + pos   -> (B, MSEQ, DDIM)
// ------------------------------------------------------------------
__global__ __launch_bounds__(256) void assemble_k(const float* __restrict__ xemb,
                                                  const float* __restrict__ cls,
                                                  const float* __restrict__ pos,
                                                  float* __restrict__ x) {
    int idx = blockIdx.x * 256 + threadIdx.x;
    if (idx >= ROWS * DDIM) return;
    int d = idx % DDIM;
    int bm = idx / DDIM;
    int m = bm % MSEQ, b = bm / MSEQ;
    float v;
    if (m == 0) v = cls[d];
    else        v = xemb[((b * NPATCH) + (m - 1)) * DDIM + d];
    x[idx] = v + pos[m * DDIM + d];
}

// ------------------------------------------------------------------
// layernorm over last dim (DDIM=192), one wave per row
// ------------------------------------------------------------------
__global__ __launch_bounds__(256) void layernorm_k(const float* __restrict__ x,
                                                   const float* __restrict__ g,
                                                   const float* __restrict__ b,
                                                   float* __restrict__ o, int nrows) {
    int wave = threadIdx.x >> 6;
    int lane = threadIdx.x & 63;
    int row = blockIdx.x * 4 + wave;
    if (row >= nrows) return;
    const float* xr = x + (long)row * DDIM;
    float v0 = xr[lane], v1 = xr[lane + 64], v2 = xr[lane + 128];
    float s = v0 + v1 + v2;
    #pragma unroll
    for (int off = 1; off < 64; off <<= 1) s += __shfl_xor(s, off);
    float mu = s * (1.f / 192.f);
    float d0 = v0 - mu, d1 = v1 - mu, d2 = v2 - mu;
    float q = d0 * d0 + d1 * d1 + d2 * d2;
    #pragma unroll
    for (int off = 1; off < 64; off <<= 1) q += __shfl_xor(q, off);
    float inv = rsqrtf(q * (1.f / 192.f) + 1e-5f);
    float* orow = o + (long)row * DDIM;
    orow[lane]       = d0 * inv * g[lane]       + b[lane];
    orow[lane + 64]  = d1 * inv * g[lane + 64]  + b[lane + 64];
    orow[lane + 128] = d2 * inv * g[lane + 128] + b[lane + 128];
}

// ------------------------------------------------------------------
// BIG fp32 GEMM for B/C projections (N=6144), tile 128x128.
// 128 threads (2 waves), per-thread 16x8 output (rows ty*16..+15,
// cols {tx*4..+3} and {64+tx*4..+3}).  WHY: the 256-thr 8x8 version
// was LDS-ISSUE-bound — per kk, 4 ds_read_b128 fed 64 FMA-instr;
// per-CU LDS cycles (768/blk/K-step) > VALU wall (512) -> VALUBusy
// 66%. 16x8 gives 6 reads per 128 FMA-instr (LDS 576 vs VALU 512).
// All LDS reads 2-way bank-aliased (free). Loads staged IMMEDIATELY
// (round-10 lesson: prefetch-early de-syncs blocks -> L2 thrash,
// FETCH 33MB -> 521MB). k-ascending per-output FMA order: bit-exact.
// gridDim.z=2 shares A; z=4 would blow L2 (round-8 lesson).
// ------------------------------------------------------------------
#define BM 128
#define BK 16
__global__ __launch_bounds__(128) void gemm_big(
        const float* __restrict__ A,
        const float* __restrict__ W0, const float* __restrict__ b0, float* __restrict__ C0,
        const float* __restrict__ W1, const float* __restrict__ b1, float* __restrict__ C1,
        int M, int N, int K) {
    const float* W    = blockIdx.z ? W1 : W0;
    const float* bias = blockIdx.z ? b1 : b0;
    float*       C    = blockIdx.z ? C1 : C0;
    __shared__ float As[BK][BM + 4];
    __shared__ float Ws[2][BK][64];
    int t = threadIdx.x;             // 0..127
    int tx = t & 15, ty = t >> 4;    // tx: 16 col-quads; ty: 8 row-groups of 16
    long colBase = (long)blockIdx.x * 128;
    int rowBase = blockIdx.y * BM;
    float acc[16][8] = {};
    // staging maps: A = one row per thread (16 k-floats);
    // W: row k0+wk, 16 consecutive cols starting at whh*64 + wn
    int ar = rowBase + t;
    const float* aptr = &A[(long)ar * K];
    int wk  = t >> 3;                // 0..15
    int whh = (t & 7) >> 2;          // panel 0/1
    int wn  = (t & 3) << 4;          // 0,16,32,48

    for (int k0 = 0; k0 < K; k0 += BK) {
        float4 av[4];
        #pragma unroll
        for (int i = 0; i < 4; ++i) av[i] = make_float4(0.f, 0.f, 0.f, 0.f);
        if (ar < M) {
            #pragma unroll
            for (int i = 0; i < 4; ++i) av[i] = *(const float4*)(aptr + k0 + i * 4);
        }
        float4 wv[4];
        #pragma unroll
        for (int i = 0; i < 4; ++i)
            wv[i] = *(const float4*)&W[(long)(k0 + wk) * N + colBase + whh * 64 + wn + i * 4];
        // stage immediately (keeps co-resident blocks k-synchronized -> L2 reuse)
        #pragma unroll
        for (int i = 0; i < 4; ++i) {
            As[i * 4 + 0][t] = av[i].x; As[i * 4 + 1][t] = av[i].y;
            As[i * 4 + 2][t] = av[i].z; As[i * 4 + 3][t] = av[i].w;
        }
        #pragma unroll
        for (int i = 0; i < 4; ++i)
            *(float4*)&Ws[whh][wk][wn + i * 4] = wv[i];
        __syncthreads();
        #pragma unroll
        for (int kk = 0; kk < BK; ++kk) {
            float a[16], w[8];
            #pragma unroll
            for (int i = 0; i < 4; ++i) {
                float4 v = *(const float4*)&As[kk][(ty << 4) + i * 4];
                a[i * 4 + 0] = v.x; a[i * 4 + 1] = v.y; a[i * 4 + 2] = v.z; a[i * 4 + 3] = v.w;
            }
            {
                float4 v0 = *(const float4*)&Ws[0][kk][tx << 2];
                float4 v1 = *(const float4*)&Ws[1][kk][tx << 2];
                w[0] = v0.x; w[1] = v0.y; w[2] = v0.z; w[3] = v0.w;
                w[4] = v1.x; w[5] = v1.y; w[6] = v1.z; w[7] = v1.w;
            }
            #pragma unroll
            for (int i = 0; i < 16; ++i)
                #pragma unroll
                for (int j = 0; j < 8; ++j)
                    acc[i][j] += a[i] * w[j];
        }
        __syncthreads();
    }
    #pragma unroll
    for (int i = 0; i < 16; ++i) {
        int r = rowBase + (ty << 4) + i;
        if (r >= M) break;
        #pragma unroll
        for (int hh = 0; hh < 2; ++hh) {
            long cb = colBase + hh * 64 + (tx << 2);
            float4 o;
            o.x = acc[i][hh * 4 + 0] + bias[cb + 0];
            o.y = acc[i][hh * 4 + 1] + bias[cb + 1];
            o.z = acc[i][hh * 4 + 2] + bias[cb + 2];
            o.w = acc[i][hh * 4 + 3] + bias[cb + 3];
            *(float4*)&C[(long)r * N + cb] = o;
        }
    }
}

// ------------------------------------------------------------------
// SMALL fp32 GEMM: one WAVE per 32x32 tile, 4x4/thread, double-
// buffered LDS. gridDim.z selects two independent sets (Wx+Wz, Df+Db).
// SP = correctly-rounded softplus epilogue. k-ascending FMA order.
// ------------------------------------------------------------------
#define SBK 16
template<bool SP, bool HASB2, bool HASRES>
__global__ __launch_bounds__(64) void gemm_s(const float* __restrict__ A0,
                                             const float* __restrict__ W0,
                                             const float* __restrict__ b10,
                                             const float* __restrict__ b20,
                                             const float* __restrict__ r0,
                                             float* __restrict__ C0,
                                             const float* __restrict__ A1,
                                             const float* __restrict__ W1,
                                             const float* __restrict__ b11,
                                             const float* __restrict__ b21,
                                             const float* __restrict__ r1,
                                             float* __restrict__ C1,
                                             int M, int N, int K) {
    const float* A  = blockIdx.z ? A1  : A0;
    const float* W  = blockIdx.z ? W1  : W0;
    const float* bp = blockIdx.z ? b11 : b10;
    const float* b2 = blockIdx.z ? b21 : b20;
    const float* rp = blockIdx.z ? r1  : r0;
    float*       C  = blockIdx.z ? C1  : C0;
    __shared__ float As[2][SBK][36];
    __shared__ float Wsh[2][SBK][36];
    int t = threadIdx.x;            // 0..63
    int tx = t & 7, ty = t >> 3;
    int rowBase = blockIdx.y * 32;
    long colBase = (long)blockIdx.x * 32;
    int rA = t >> 2, kqA = (t & 3) << 2;
    int kW = t >> 3, nqW = (t & 7) << 2;
    float acc[4][4] = {};
    int r0i = rowBase + rA, r1i = r0i + 16;

    auto loadA = [&](int k0, float4& a0, float4& a1) {
        a0 = make_float4(0.f,0.f,0.f,0.f); a1 = a0;
        if (r0i < M) a0 = *(const float4*)&A[(long)r0i * K + k0 + kqA];
        if (r1i < M) a1 = *(const float4*)&A[(long)r1i * K + k0 + kqA];
    };
    auto stage = [&](int buf, float4 a0, float4 a1, float4 w0, float4 w1) {
        As[buf][kqA + 0][rA] = a0.x; As[buf][kqA + 1][rA] = a0.y;
        As[buf][kqA + 2][rA] = a0.z; As[buf][kqA + 3][rA] = a0.w;
        As[buf][kqA + 0][rA + 16] = a1.x; As[buf][kqA + 1][rA + 16] = a1.y;
        As[buf][kqA + 2][rA + 16] = a1.z; As[buf][kqA + 3][rA + 16] = a1.w;
        *(float4*)&Wsh[buf][kW][nqW]     = w0;
        *(float4*)&Wsh[buf][kW + 8][nqW] = w1;
    };
    auto compute = [&](int buf) {
        #pragma unroll
        for (int kk = 0; kk < SBK; ++kk) {
            float4 av = *(const float4*)&As[buf][kk][ty << 2];
            float4 wv = *(const float4*)&Wsh[buf][kk][tx << 2];
            float ar[4] = {av.x, av.y, av.z, av.w};
            float wr[4] = {wv.x, wv.y, wv.z, wv.w};
            #pragma unroll
            for (int i = 0; i < 4; ++i)
                #pragma unroll
                for (int j = 0; j < 4; ++j) acc[i][j] += ar[i] * wr[j];
        }
    };

    {
        float4 a0, a1;
        loadA(0, a0, a1);
        float4 w0 = *(const float4*)&W[(long)kW * N + colBase + nqW];
        float4 w1 = *(const float4*)&W[(long)(kW + 8) * N + colBase + nqW];
        stage(0, a0, a1, w0, w1);
    }
    __syncthreads();
    int cur = 0;
    int nt = K / SBK;
    for (int kt = 1; kt < nt; ++kt) {
        int k0 = kt * SBK;
        float4 a0, a1;
        loadA(k0, a0, a1);
        float4 w0 = *(const float4*)&W[(long)(k0 + kW) * N + colBase + nqW];
        float4 w1 = *(const float4*)&W[(long)(k0 + kW + 8) * N + colBase + nqW];
        compute(cur);
        stage(cur ^ 1, a0, a1, w0, w1);
        __syncthreads();
        cur ^= 1;
    }
    compute(cur);

    #pragma unroll
    for (int i = 0; i < 4; ++i) {
        int r = rowBase + (ty << 2) + i;
        if (r >= M) break;
        long cb = colBase + (tx << 2);
        float vv[4];
        #pragma unroll
        for (int j = 0; j < 4; ++j) {
            float v = acc[i][j] + bp[cb + j];
            if (HASB2) v += b2[cb + j];
            if (SP) {  // correctly-rounded fp32 softplus via fp64
                double vd = (double)v;
                v = (float)(log1p(exp(-fabs(vd))) + fmax(vd, 0.0));
            }
            if (HASRES) v += rp[(long)r * N + cb + j];
            vv[j] = v;
        }
        float4 o; o.x = vv[0]; o.y = vv[1]; o.z = vv[2]; o.w = vv[3];
        *(float4*)&C[(long)r * N + cb] = o;
    }
}

// ------------------------------------------------------------------
// fused depthwise conv (fwd + bwd) + SiLU
// ------------------------------------------------------------------
__global__ __launch_bounds__(256) void dwconv_k(const float* __restrict__ xp,
                                                const float* __restrict__ wf,
                                                const float* __restrict__ bf,
                                                const float* __restrict__ wb,
                                                const float* __restrict__ bb,
                                                float* __restrict__ xf,
                                                float* __restrict__ xb) {
    int idx = blockIdx.x * 256 + threadIdx.x;
    if (idx >= ROWS * EDIM) return;
    int e = idx % EDIM;
    int bm = idx / EDIM;
    int m = bm % MSEQ, b = bm / MSEQ;
    const float* base = xp + (long)b * MSEQ * EDIM + e;
    float xm1 = (m > 0)        ? base[(m - 1) * EDIM] : 0.f;
    float x0  =                  base[m * EDIM];
    float xp1 = (m < MSEQ - 1) ? base[(m + 1) * EDIM] : 0.f;
    float f = wf[e * 3 + 0] * xm1 + wf[e * 3 + 1] * x0 + wf[e * 3 + 2] * xp1 + bf[e];
    float r = wb[e * 3 + 0] * xp1 + wb[e * 3 + 1] * x0 + wb[e * 3 + 2] * xm1 + bb[e];
    xf[idx] = silu_f(f);
    xb[idx] = silu_f(r);
}

// ------------------------------------------------------------------
// SSM recurrence, PHASE-PARALLEL, bit-exact vs the sequential scan
// (same fp32 op order in every chain). One block per (b,e).
// ------------------------------------------------------------------
__global__ __launch_bounds__(256) void ssm_scan_k(const float* __restrict__ Bm,
                                                  const float* __restrict__ Cm,
                                                  const float* __restrict__ Dlt,
                                                  const float* __restrict__ xs,
                                                  const float* __restrict__ Apar,
                                                  float* __restrict__ y) {
#pragma clang fp contract(off)
    __shared__ float lgP[MSEQ][17];        // lg -> cumlog -> P
    __shared__ float trm[MSEQ][17];        // term -> h
    __shared__ signed char sgn[MSEQ][17];  // sa -> cumsign
    int be = blockIdx.x;
    int b = be / EDIM, e = be - b * EDIM;
    int t = threadIdx.x;
    int n0 = t & 15;                       // fixed per thread (256 % 16 == 0)
    float Ap = Apar[e * NSTATE + n0];
    const long dxBase = (long)b * MSEQ * EDIM + e;
    const long bcBase = (long)b * MSEQ * ENDIM + e * NSTATE;

    // phase 1
    for (int idx = t; idx < MSEQ * NSTATE; idx += 256) {
        int m = idx >> 4;
        float delta = Dlt[dxBase + (long)m * EDIM];
        float A = delta * Ap;                              // exact fp32 product
        float sa = (A > 0.f) ? 1.f : ((A < 0.f) ? -1.f : 0.f);
        float absA = fmaxf(fabsf(A), 1e-6f);
        lgP[m][n0] = (float)log((double)absA);             // CR fp32 log
        sgn[m][n0] = (signed char)sa;
    }
    __syncthreads();
    // phase 2: serial per n — identical add order to the sequential scan
    if (t < NSTATE) {
        float cl = 0.f, cs = 1.f;
        for (int m = 0; m < MSEQ; ++m) {
            float sa = (float)sgn[m][t];
            cs = cs * sa;
            cl = cl + lgP[m][t];
            lgP[m][t] = cl;
            sgn[m][t] = (signed char)cs;
        }
    }
    __syncthreads();
    // phase 3
    for (int idx = t; idx < MSEQ * NSTATE; idx += 256) {
        int m = idx >> 4;
        float cl = lgP[m][n0];
        float cs = (float)sgn[m][n0];
        float ex = (float)exp((double)cl);                 // CR fp32 exp
        float P = cs * ex;
        float tt = P + 1e-6f;                              // exact near-cancel
        float invP = 1.0f / tt;                            // IEEE fp32 div
        float delta = Dlt[dxBase + (long)m * EDIM];
        float xv = xs[dxBase + (long)m * EDIM];
        float Bv = Bm[bcBase + (long)m * ENDIM + n0];
        float Bfull = delta * Bv;
        float t1 = invP * Bfull;
        float t2 = t1 * xv;
        trm[m][n0] = t2;
        lgP[m][n0] = P;
    }
    __syncthreads();
    // phase 4: serial per n — identical add order
    if (t < NSTATE) {
        float S = 0.f;
        for (int m = 0; m < MSEQ; ++m) {
            S = S + trm[m][t];
            float h = lgP[m][t] * S;
            trm[m][t] = h;
        }
    }
    __syncthreads();
    // phase 5: numpy pairwise-16 tree (xor8, xor1, xor2, xor4; lane-0 order)
    for (int m = t; m < MSEQ; m += 256) {
        const float* cp = &Cm[bcBase + (long)m * ENDIM];
        float a[16];
        #pragma unroll
        for (int n = 0; n < 16; ++n) a[n] = trm[m][n] * cp[n];
        float b0 = a[0] + a[8],  b1 = a[1] + a[9];
        float b2v = a[2] + a[10], b3 = a[3] + a[11];
        float b4 = a[4] + a[12], b5 = a[5] + a[13];
        float b6 = a[6] + a[14], b7 = a[7] + a[15];
        float c0 = b0 + b1, c2 = b2v + b3, c4 = b4 + b5, c6 = b6 + b7;
        float d0 = c0 + c2, d4 = c4 + c6;
        y[dxBase + (long)m * EDIM] = d0 + d4;
    }
}

// ------------------------------------------------------------------
// combine: yc = (yf + yb) * silu(z)
// ------------------------------------------------------------------
__global__ __launch_bounds__(256) void combine_k(const float* __restrict__ yf,
                                                 const float* __restrict__ yb,
                                                 const float* __restrict__ z,
                                                 float* __restrict__ yc) {
    int idx = blockIdx.x * 256 + threadIdx.x;
    if (idx >= ROWS * EDIM) return;
    yc[idx] = (yf[idx] + yb[idx]) * silu_f(z[idx]);
}

extern "C" void kernel_launch(void* const* d_in, const int* in_sizes, int n_in,
                              void* d_out, int out_size, void* d_ws, size_t ws_size,
                              hipStream_t stream) {
    const float* img     = (const float*)d_in[0];
    const float* patch_w = (const float*)d_in[1];
    const float* patch_b = (const float*)d_in[2];
    const float* cls     = (const float*)d_in[3];
    const float* pos     = (const float*)d_in[4];
    const float* ln_g    = (const float*)d_in[5];
    const float* ln_b    = (const float*)d_in[6];
    const float* Wx  = (const float*)d_in[7];  const float* bx  = (const float*)d_in[8];
    const float* Wz  = (const float*)d_in[9];  const float* bz  = (const float*)d_in[10];
    const float* cwf = (const float*)d_in[11]; const float* cbf = (const float*)d_in[12];
    const float* cwb = (const float*)d_in[13]; const float* cbb = (const float*)d_in[14];
    const float* WBf = (const float*)d_in[15]; const float* bBf = (const float*)d_in[16];
    const float* WCf = (const float*)d_in[17]; const float* bCf = (const float*)d_in[18];
    const float* WDf = (const float*)d_in[19]; const float* bDf = (const float*)d_in[20];
    const float* Af  = (const float*)d_in[21]; const float* dbf = (const float*)d_in[22];
    const float* WBb = (const float*)d_in[23]; const float* bBb = (const float*)d_in[24];
    const float* WCb = (const float*)d_in[25]; const float* bCb = (const float*)d_in[26];
    const float* WDb = (const float*)d_in[27]; const float* bDb = (const float*)d_in[28];
    const float* Ab  = (const float*)d_in[29]; const float* dbb = (const float*)d_in[30];
    const float* Wout= (const float*)d_in[31]; const float* bout= (const float*)d_in[32];
    const float* ng  = (const float*)d_in[33]; const float* nb  = (const float*)d_in[34];

    float* ws = (float*)d_ws;
    float* xA   = ws;
    float* xB   = xA  + (size_t)ROWS * DDIM;
    float* xn   = xB  + (size_t)ROWS * DDIM;
    float* xp   = xn  + (size_t)ROWS * DDIM;
    float* zb   = xp  + (size_t)ROWS * EDIM;
    float* xfb  = zb  + (size_t)ROWS * EDIM;
    float* xbb  = xfb + (size_t)ROWS * EDIM;
    float* yfb  = xbb + (size_t)ROWS * EDIM;
    float* ybb  = yfb + (size_t)ROWS * EDIM;
    float* ycb  = ybb + (size_t)ROWS * EDIM;
    float* dlt  = ycb + (size_t)ROWS * EDIM;
    float* dlt2 = dlt + (size_t)ROWS * EDIM;
    float* Bmb  = dlt2 + (size_t)ROWS * EDIM;         // ROWS*ENDIM
    float* Cmb  = Bmb + (size_t)ROWS * ENDIM;
    // patchify scratch aliases the (not-yet-needed) B buffer
    float* patches = Bmb;                             // PROWS*PATCH_K
    float* xemb    = Bmb + (size_t)PROWS * PATCH_K;   // PROWS*DDIM

    // --- patch embedding ---
    patchify_k<<<(PROWS * PATCH_K + 255) / 256, 256, 0, stream>>>(img, patches);
    {   // 1568x192x768 GEMM
        dim3 g(DDIM / 32, (PROWS + 31) / 32, 1);
        gemm_s<false, false, false><<<g, 64, 0, stream>>>(
            patches, patch_w, patch_b, nullptr, nullptr, xemb,
            patches, patch_w, patch_b, nullptr, nullptr, xemb,
            PROWS, DDIM, PATCH_K);
    }
    assemble_k<<<(ROWS * DDIM + 255) / 256, 256, 0, stream>>>(xemb, cls, pos, xA);

    float* cur = xA; float* nxt = xB;
    for (int i = 0; i < LLAYERS; ++i) {
        layernorm_k<<<(ROWS + 3) / 4, 256, 0, stream>>>(cur, ln_g + i * DDIM, ln_b + i * DDIM, xn, ROWS);
        {   // Wx + Wz fused (shared A=xn)
            dim3 g(EDIM / 32, (ROWS + 31) / 32, 2);
            gemm_s<false, false, false><<<g, 64, 0, stream>>>(
                xn, Wx + (size_t)i * DDIM * EDIM, bx + i * EDIM, nullptr, nullptr, xp,
                xn, Wz + (size_t)i * DDIM * EDIM, bz + i * EDIM, nullptr, nullptr, zb,
                ROWS, EDIM, DDIM);
        }
        dwconv_k<<<(ROWS * EDIM + 255) / 256, 256, 0, stream>>>(xp, cwf + i * EDIM * 3, cbf + i * EDIM,
                                                                cwb + i * EDIM * 3, cbb + i * EDIM, xfb, xbb);
        {   // Df + Db fused (CR softplus epilogue)
            dim3 g(EDIM / 32, (ROWS + 31) / 32, 2);
            gemm_s<true, true, false><<<g, 64, 0, stream>>>(
                xfb, WDf + (size_t)i * EDIM * EDIM, bDf + i * EDIM, dbf + i * EDIM, nullptr, dlt,
                xbb, WDb + (size_t)i * EDIM * EDIM, bDb + i * EDIM, dbb + i * EDIM, nullptr, dlt2,
                ROWS, EDIM, EDIM);
        }
        {   // Bf + Cf fused z=2 (shared A=xfb; W set 18.8MB = L2-resident)
            dim3 g(ENDIM / 128, (ROWS + BM - 1) / BM, 2);
            gemm_big<<<g, 128, 0, stream>>>(
                xfb,
                WBf + (size_t)i * EDIM * ENDIM, bBf + i * ENDIM, Bmb,
                WCf + (size_t)i * EDIM * ENDIM, bCf + i * ENDIM, Cmb,
                ROWS, ENDIM, EDIM);
        }
        ssm_scan_k<<<BATCH * EDIM, 256, 0, stream>>>(Bmb, Cmb, dlt, xfb, Af + i * EDIM * NSTATE, yfb);
        {   // Bb + Cb fused z=2 (shared A=xbb)
            dim3 g(ENDIM / 128, (ROWS + BM - 1) / BM, 2);
            gemm_big<<<g, 128, 0, stream>>>(
                xbb,
                WBb + (size_t)i * EDIM * ENDIM, bBb + i * ENDIM, Bmb,
                WCb + (size_t)i * EDIM * ENDIM, bCb + i * ENDIM, Cmb,
                ROWS, ENDIM, EDIM);
        }
        ssm_scan_k<<<BATCH * EDIM, 256, 0, stream>>>(Bmb, Cmb, dlt2, xbb, Ab + i * EDIM * NSTATE, ybb);

        combine_k<<<(ROWS * EDIM + 255) / 256, 256, 0, stream>>>(yfb, ybb, zb, ycb);
        {   // Wout with residual
            dim3 g(DDIM / 32, (ROWS + 31) / 32, 1);
            gemm_s<false, false, true><<<g, 64, 0, stream>>>(
                ycb, Wout + (size_t)i * EDIM * DDIM, bout + i * DDIM, nullptr, cur, nxt,
                ycb, Wout + (size_t)i * EDIM * DDIM, bout + i * DDIM, nullptr, cur, nxt,
                ROWS, DDIM, EDIM);
        }
        float* t = cur; cur = nxt; nxt = t;
    }
    layernorm_k<<<(ROWS + 3) / 4, 256, 0, stream>>>(cur, ng, nb, (float*)d_out, ROWS);
}

// Round 12
// 1199.376 us; speedup vs baseline: 1.1041x; 1.1041x over previous
//
#include <hip/hip_runtime.h>
#include <hip/hip_bf16.h>
#include <math.h>

// ---- problem constants ----
#define BATCH   8
#define C_IN    3
#define IMG_SZ  224
#define P_SZ    16
#define NPATCH  196                 // (224/16)^2
#define MSEQ    197                 // NPATCH + cls
#define DDIM    192
#define EDIM    384
#define NSTATE  16
#define ENDIM   (EDIM*NSTATE)       // 6144
#define LLAYERS 2
#define ROWS    (BATCH*MSEQ)        // 1576
#define PROWS   (BATCH*NPATCH)      // 1568
#define PATCH_K (C_IN*P_SZ*P_SZ)    // 768

// precise silu (enters the scan only linearly)
__device__ __forceinline__ float silu_f(float x) { return x / (1.f + expf(-x)); }

// ------------------------------------------------------------------
// patchify: img (B,3,224,224) -> patches (PROWS, 768)
// ------------------------------------------------------------------
__global__ __launch_bounds__(256) void patchify_k(const float* __restrict__ img,
                                                  float* __restrict__ out) {
    int idx = blockIdx.x * 256 + threadIdx.x;
    if (idx >= PROWS * PATCH_K) return;
    int r = idx / PATCH_K, col = idx - r * PATCH_K;
    int b = r / NPATCH, p = r - b * NPATCH;
    int ph = p / 14, pw = p - ph * 14;
    int c = col >> 8, rem = col & 255, py = rem >> 4, px = rem & 15;
    out[idx] = img[((b * C_IN + c) * IMG_SZ + ph * P_SZ + py) * IMG_SZ + pw * P_SZ + px];
}

// ------------------------------------------------------------------
// assemble x = concat(cls, xemb) + pos   -> (B, MSEQ, DDIM)
// ------------------------------------------------------------------
__global__ __launch_bounds__(256) void assemble_k(const float* __restrict__ xemb,
                                                  const float* __restrict__ cls,
                                                  const float* __restrict__ pos,
                                                  float* __restrict__ x) {
    int idx = blockIdx.x * 256 + threadIdx.x;
    if (idx >= ROWS * DDIM) return;
    int d = idx % DDIM;
    int bm = idx / DDIM;
    int m = bm % MSEQ, b = bm / MSEQ;
    float v;
    if (m == 0) v = cls[d];
    else        v = xemb[((b * NPATCH) + (m - 1)) * DDIM + d];
    x[idx] = v + pos[m * DDIM + d];
}

// ------------------------------------------------------------------
// layernorm over last dim (DDIM=192), one wave per row
// ------------------------------------------------------------------
__global__ __launch_bounds__(256) void layernorm_k(const float* __restrict__ x,
                                                   const float* __restrict__ g,
                                                   const float* __restrict__ b,
                                                   float* __restrict__ o, int nrows) {
    int wave = threadIdx.x >> 6;
    int lane = threadIdx.x & 63;
    int row = blockIdx.x * 4 + wave;
    if (row >= nrows) return;
    const float* xr = x + (long)row * DDIM;
    float v0 = xr[lane], v1 = xr[lane + 64], v2 = xr[lane + 128];
    float s = v0 + v1 + v2;
    #pragma unroll
    for (int off = 1; off < 64; off <<= 1) s += __shfl_xor(s, off);
    float mu = s * (1.f / 192.f);
    float d0 = v0 - mu, d1 = v1 - mu, d2 = v2 - mu;
    float q = d0 * d0 + d1 * d1 + d2 * d2;
    #pragma unroll
    for (int off = 1; off < 64; off <<= 1) q += __shfl_xor(q, off);
    float inv = rsqrtf(q * (1.f / 192.f) + 1e-5f);
    float* orow = o + (long)row * DDIM;
    orow[lane]       = d0 * inv * g[lane]       + b[lane];
    orow[lane + 64]  = d1 * inv * g[lane + 64]  + b[lane + 64];
    orow[lane + 128] = d2 * inv * g[lane + 128] + b[lane + 128];
}

// ------------------------------------------------------------------
// BIG fp32 GEMM for B/C projections (N=6144), tile 128x128, 8x8 per
// thread, 256 threads — ROUND-10 structure (proven: 195us, FETCH
// 33MB, VALUBusy 66% = the structural LDS-issue ceiling for r=c=8;
// r*c >= 6(r+c) needed to beat it, which spills without MFMA) with
// ONE change: BK=32 halves the barrier count (24 steps, 2 bar/step
// -> 12 steps). LDS 33.4KB still fits 4 blocks/CU. Loads staged
// IMMEDIATELY (r9/r10 lesson: early prefetch de-syncs co-resident
// blocks -> W panels fall out of L2 -> 16x HBM over-fetch).
// k-ascending per-output FMA order: bit-exact vs all prior rounds.
// gridDim.z=2 shares A; z=4 blows L2 (r8 lesson).
// ------------------------------------------------------------------
#define BM 128
#define BK 32
__global__ __launch_bounds__(256) void gemm_big(
        const float* __restrict__ A,
        const float* __restrict__ W0, const float* __restrict__ b0, float* __restrict__ C0,
        const float* __restrict__ W1, const float* __restrict__ b1, float* __restrict__ C1,
        int M, int N, int K) {
    const float* W    = blockIdx.z ? W1 : W0;
    const float* bias = blockIdx.z ? b1 : b0;
    float*       C    = blockIdx.z ? C1 : C0;
    __shared__ float As[BK][BM + 4];
    __shared__ float Ws[2][BK][64];
    int t = threadIdx.x;
    int tx = t & 15, ty = t >> 4;
    long colBase = (long)blockIdx.x * 128;
    int rowBase = blockIdx.y * BM;
    float acc[8][8] = {};
    int a_m = t >> 1, a_k = (t & 1) << 4;      // A: 4 float4 per thread (16 floats)
    int w_k = t >> 4, w_n = (t & 15) << 2;     // W: rows w_k, w_k+16; both panels
    int ar = rowBase + a_m;
    for (int k0 = 0; k0 < K; k0 += BK) {
        float4 av[4];
        #pragma unroll
        for (int i = 0; i < 4; ++i) av[i] = make_float4(0.f, 0.f, 0.f, 0.f);
        if (ar < M) {
            const float* ap = &A[(long)ar * K + k0 + a_k];
            #pragma unroll
            for (int i = 0; i < 4; ++i) av[i] = *(const float4*)(ap + i * 4);
        }
        #pragma unroll
        for (int i = 0; i < 4; ++i) {
            As[a_k + i * 4 + 0][a_m] = av[i].x;
            As[a_k + i * 4 + 1][a_m] = av[i].y;
            As[a_k + i * 4 + 2][a_m] = av[i].z;
            As[a_k + i * 4 + 3][a_m] = av[i].w;
        }
        #pragma unroll
        for (int kr = 0; kr < 2; ++kr)
            #pragma unroll
            for (int hh = 0; hh < 2; ++hh)
                *(float4*)&Ws[hh][w_k + kr * 16][w_n] =
                    *(const float4*)&W[(long)(k0 + w_k + kr * 16) * N + colBase + hh * 64 + w_n];
        __syncthreads();
        #pragma unroll
        for (int kk = 0; kk < BK; ++kk) {
            float4 a0 = *(const float4*)&As[kk][ty << 3];
            float4 a1 = *(const float4*)&As[kk][(ty << 3) + 4];
            float ar8[8] = {a0.x, a0.y, a0.z, a0.w, a1.x, a1.y, a1.z, a1.w};
            #pragma unroll
            for (int hh = 0; hh < 2; ++hh) {
                float4 w = *(const float4*)&Ws[hh][kk][tx << 2];
                float wr[4] = {w.x, w.y, w.z, w.w};
                #pragma unroll
                for (int i = 0; i < 8; ++i)
                    #pragma unroll
                    for (int j = 0; j < 4; ++j)
                        acc[i][hh * 4 + j] += ar8[i] * wr[j];
            }
        }
        __syncthreads();
    }
    #pragma unroll
    for (int i = 0; i < 8; ++i) {
        int r = rowBase + (ty << 3) + i;
        if (r >= M) break;
        #pragma unroll
        for (int hh = 0; hh < 2; ++hh) {
            long cb = colBase + hh * 64 + (tx << 2);
            float4 o;
            o.x = acc[i][hh * 4 + 0] + bias[cb + 0];
            o.y = acc[i][hh * 4 + 1] + bias[cb + 1];
            o.z = acc[i][hh * 4 + 2] + bias[cb + 2];
            o.w = acc[i][hh * 4 + 3] + bias[cb + 3];
            *(float4*)&C[(long)r * N + cb] = o;
        }
    }
}

// ------------------------------------------------------------------
// SMALL fp32 GEMM: one WAVE per 32x32 tile, 4x4/thread, double-
// buffered LDS. gridDim.z selects two independent sets (Wx+Wz, Df+Db).
// SP = correctly-rounded softplus epilogue. k-ascending FMA order.
// ------------------------------------------------------------------
#define SBK 16
template<bool SP, bool HASB2, bool HASRES>
__global__ __launch_bounds__(64) void gemm_s(const float* __restrict__ A0,
                                             const float* __restrict__ W0,
                                             const float* __restrict__ b10,
                                             const float* __restrict__ b20,
                                             const float* __restrict__ r0,
                                             float* __restrict__ C0,
                                             const float* __restrict__ A1,
                                             const float* __restrict__ W1,
                                             const float* __restrict__ b11,
                                             const float* __restrict__ b21,
                                             const float* __restrict__ r1,
                                             float* __restrict__ C1,
                                             int M, int N, int K) {
    const float* A  = blockIdx.z ? A1  : A0;
    const float* W  = blockIdx.z ? W1  : W0;
    const float* bp = blockIdx.z ? b11 : b10;
    const float* b2 = blockIdx.z ? b21 : b20;
    const float* rp = blockIdx.z ? r1  : r0;
    float*       C  = blockIdx.z ? C1  : C0;
    __shared__ float As[2][SBK][36];
    __shared__ float Wsh[2][SBK][36];
    int t = threadIdx.x;            // 0..63
    int tx = t & 7, ty = t >> 3;
    int rowBase = blockIdx.y * 32;
    long colBase = (long)blockIdx.x * 32;
    int rA = t >> 2, kqA = (t & 3) << 2;
    int kW = t >> 3, nqW = (t & 7) << 2;
    float acc[4][4] = {};
    int r0i = rowBase + rA, r1i = r0i + 16;

    auto loadA = [&](int k0, float4& a0, float4& a1) {
        a0 = make_float4(0.f,0.f,0.f,0.f); a1 = a0;
        if (r0i < M) a0 = *(const float4*)&A[(long)r0i * K + k0 + kqA];
        if (r1i < M) a1 = *(const float4*)&A[(long)r1i * K + k0 + kqA];
    };
    auto stage = [&](int buf, float4 a0, float4 a1, float4 w0, float4 w1) {
        As[buf][kqA + 0][rA] = a0.x; As[buf][kqA + 1][rA] = a0.y;
        As[buf][kqA + 2][rA] = a0.z; As[buf][kqA + 3][rA] = a0.w;
        As[buf][kqA + 0][rA + 16] = a1.x; As[buf][kqA + 1][rA + 16] = a1.y;
        As[buf][kqA + 2][rA + 16] = a1.z; As[buf][kqA + 3][rA + 16] = a1.w;
        *(float4*)&Wsh[buf][kW][nqW]     = w0;
        *(float4*)&Wsh[buf][kW + 8][nqW] = w1;
    };
    auto compute = [&](int buf) {
        #pragma unroll
        for (int kk = 0; kk < SBK; ++kk) {
            float4 av = *(const float4*)&As[buf][kk][ty << 2];
            float4 wv = *(const float4*)&Wsh[buf][kk][tx << 2];
            float ar[4] = {av.x, av.y, av.z, av.w};
            float wr[4] = {wv.x, wv.y, wv.z, wv.w};
            #pragma unroll
            for (int i = 0; i < 4; ++i)
                #pragma unroll
                for (int j = 0; j < 4; ++j) acc[i][j] += ar[i] * wr[j];
        }
    };

    {
        float4 a0, a1;
        loadA(0, a0, a1);
        float4 w0 = *(const float4*)&W[(long)kW * N + colBase + nqW];
        float4 w1 = *(const float4*)&W[(long)(kW + 8) * N + colBase + nqW];
        stage(0, a0, a1, w0, w1);
    }
    __syncthreads();
    int cur = 0;
    int nt = K / SBK;
    for (int kt = 1; kt < nt; ++kt) {
        int k0 = kt * SBK;
        float4 a0, a1;
        loadA(k0, a0, a1);
        float4 w0 = *(const float4*)&W[(long)(k0 + kW) * N + colBase + nqW];
        float4 w1 = *(const float4*)&W[(long)(k0 + kW + 8) * N + colBase + nqW];
        compute(cur);
        stage(cur ^ 1, a0, a1, w0, w1);
        __syncthreads();
        cur ^= 1;
    }
    compute(cur);

    #pragma unroll
    for (int i = 0; i < 4; ++i) {
        int r = rowBase + (ty << 2) + i;
        if (r >= M) break;
        long cb = colBase + (tx << 2);
        float vv[4];
        #pragma unroll
        for (int j = 0; j < 4; ++j) {
            float v = acc[i][j] + bp[cb + j];
            if (HASB2) v += b2[cb + j];
            if (SP) {  // correctly-rounded fp32 softplus via fp64
                double vd = (double)v;
                v = (float)(log1p(exp(-fabs(vd))) + fmax(vd, 0.0));
            }
            if (HASRES) v += rp[(long)r * N + cb + j];
            vv[j] = v;
        }
        float4 o; o.x = vv[0]; o.y = vv[1]; o.z = vv[2]; o.w = vv[3];
        *(float4*)&C[(long)r * N + cb] = o;
    }
}

// ------------------------------------------------------------------
// fused depthwise conv (fwd + bwd) + SiLU
// ------------------------------------------------------------------
__global__ __launch_bounds__(256) void dwconv_k(const float* __restrict__ xp,
                                                const float* __restrict__ wf,
                                                const float* __restrict__ bf,
                                                const float* __restrict__ wb,
                                                const float* __restrict__ bb,
                                                float* __restrict__ xf,
                                                float* __restrict__ xb) {
    int idx = blockIdx.x * 256 + threadIdx.x;
    if (idx >= ROWS * EDIM) return;
    int e = idx % EDIM;
    int bm = idx / EDIM;
    int m = bm % MSEQ, b = bm / MSEQ;
    const float* base = xp + (long)b * MSEQ * EDIM + e;
    float xm1 = (m > 0)        ? base[(m - 1) * EDIM] : 0.f;
    float x0  =                  base[m * EDIM];
    float xp1 = (m < MSEQ - 1) ? base[(m + 1) * EDIM] : 0.f;
    float f = wf[e * 3 + 0] * xm1 + wf[e * 3 + 1] * x0 + wf[e * 3 + 2] * xp1 + bf[e];
    float r = wb[e * 3 + 0] * xp1 + wb[e * 3 + 1] * x0 + wb[e * 3 + 2] * xm1 + bb[e];
    xf[idx] = silu_f(f);
    xb[idx] = silu_f(r);
}

// ------------------------------------------------------------------
// SSM recurrence, PHASE-PARALLEL, bit-exact vs the sequential scan
// (same fp32 op order in every chain). One block per (b,e).
// If ycomb != nullptr, phase 5 fuses the combine step:
//   ycomb = (yother + y_this) * silu(zg)   — same fp32 expression as
// the old combine_k kernel (bit-identical), saving one launch.
// ------------------------------------------------------------------
__global__ __launch_bounds__(256) void ssm_scan_k(const float* __restrict__ Bm,
                                                  const float* __restrict__ Cm,
                                                  const float* __restrict__ Dlt,
                                                  const float* __restrict__ xs,
                                                  const float* __restrict__ Apar,
                                                  float* __restrict__ y,
                                                  const float* __restrict__ yother,
                                                  const float* __restrict__ zg,
                                                  float* __restrict__ ycomb) {
#pragma clang fp contract(off)
    __shared__ float lgP[MSEQ][17];        // lg -> cumlog -> P
    __shared__ float trm[MSEQ][17];        // term -> h
    __shared__ signed char sgn[MSEQ][17];  // sa -> cumsign
    int be = blockIdx.x;
    int b = be / EDIM, e = be - b * EDIM;
    int t = threadIdx.x;
    int n0 = t & 15;                       // fixed per thread (256 % 16 == 0)
    float Ap = Apar[e * NSTATE + n0];
    const long dxBase = (long)b * MSEQ * EDIM + e;
    const long bcBase = (long)b * MSEQ * ENDIM + e * NSTATE;

    // phase 1
    for (int idx = t; idx < MSEQ * NSTATE; idx += 256) {
        int m = idx >> 4;
        float delta = Dlt[dxBase + (long)m * EDIM];
        float A = delta * Ap;                              // exact fp32 product
        float sa = (A > 0.f) ? 1.f : ((A < 0.f) ? -1.f : 0.f);
        float absA = fmaxf(fabsf(A), 1e-6f);
        lgP[m][n0] = (float)log((double)absA);             // CR fp32 log
        sgn[m][n0] = (signed char)sa;
    }
    __syncthreads();
    // phase 2: serial per n — identical add order to the sequential scan
    if (t < NSTATE) {
        float cl = 0.f, cs = 1.f;
        for (int m = 0; m < MSEQ; ++m) {
            float sa = (float)sgn[m][t];
            cs = cs * sa;
            cl = cl + lgP[m][t];
            lgP[m][t] = cl;
            sgn[m][t] = (signed char)cs;
        }
    }
    __syncthreads();
    // phase 3
    for (int idx = t; idx < MSEQ * NSTATE; idx += 256) {
        int m = idx >> 4;
        float cl = lgP[m][n0];
        float cs = (float)sgn[m][n0];
        float ex = (float)exp((double)cl);                 // CR fp32 exp
        float P = cs * ex;
        float tt = P + 1e-6f;                              // exact near-cancel
        float invP = 1.0f / tt;                            // IEEE fp32 div
        float delta = Dlt[dxBase + (long)m * EDIM];
        float xv = xs[dxBase + (long)m * EDIM];
        float Bv = Bm[bcBase + (long)m * ENDIM + n0];
        float Bfull = delta * Bv;
        float t1 = invP * Bfull;
        float t2 = t1 * xv;
        trm[m][n0] = t2;
        lgP[m][n0] = P;
    }
    __syncthreads();
    // phase 4: serial per n — identical add order
    if (t < NSTATE) {
        float S = 0.f;
        for (int m = 0; m < MSEQ; ++m) {
            S = S + trm[m][t];
            float h = lgP[m][t] * S;
            trm[m][t] = h;
        }
    }
    __syncthreads();
    // phase 5: numpy pairwise-16 tree (xor8, xor1, xor2, xor4; lane-0 order)
    for (int m = t; m < MSEQ; m += 256) {
        const float* cp = &Cm[bcBase + (long)m * ENDIM];
        float a[16];
        #pragma unroll
        for (int n = 0; n < 16; ++n) a[n] = trm[m][n] * cp[n];
        float b0 = a[0] + a[8],  b1 = a[1] + a[9];
        float b2v = a[2] + a[10], b3 = a[3] + a[11];
        float b4 = a[4] + a[12], b5 = a[5] + a[13];
        float b6 = a[6] + a[14], b7 = a[7] + a[15];
        float c0 = b0 + b1, c2 = b2v + b3, c4 = b4 + b5, c6 = b6 + b7;
        float d0 = c0 + c2, d4 = c4 + c6;
        float val = d0 + d4;
        long o = dxBase + (long)m * EDIM;
        if (ycomb) ycomb[o] = (yother[o] + val) * silu_f(zg[o]);
        else       y[o] = val;
    }
}

extern "C" void kernel_launch(void* const* d_in, const int* in_sizes, int n_in,
                              void* d_out, int out_size, void* d_ws, size_t ws_size,
                              hipStream_t stream) {
    const float* img     = (const float*)d_in[0];
    const float* patch_w = (const float*)d_in[1];
    const float* patch_b = (const float*)d_in[2];
    const float* cls     = (const float*)d_in[3];
    const float* pos     = (const float*)d_in[4];
    const float* ln_g    = (const float*)d_in[5];
    const float* ln_b    = (const float*)d_in[6];
    const float* Wx  = (const float*)d_in[7];  const float* bx  = (const float*)d_in[8];
    const float* Wz  = (const float*)d_in[9];  const float* bz  = (const float*)d_in[10];
    const float* cwf = (const float*)d_in[11]; const float* cbf = (const float*)d_in[12];
    const float* cwb = (const float*)d_in[13]; const float* cbb = (const float*)d_in[14];
    const float* WBf = (const float*)d_in[15]; const float* bBf = (const float*)d_in[16];
    const float* WCf = (const float*)d_in[17]; const float* bCf = (const float*)d_in[18];
    const float* WDf = (const float*)d_in[19]; const float* bDf = (const float*)d_in[20];
    const float* Af  = (const float*)d_in[21]; const float* dbf = (const float*)d_in[22];
    const float* WBb = (const float*)d_in[23]; const float* bBb = (const float*)d_in[24];
    const float* WCb = (const float*)d_in[25]; const float* bCb = (const float*)d_in[26];
    const float* WDb = (const float*)d_in[27]; const float* bDb = (const float*)d_in[28];
    const float* Ab  = (const float*)d_in[29]; const float* dbb = (const float*)d_in[30];
    const float* Wout= (const float*)d_in[31]; const float* bout= (const float*)d_in[32];
    const float* ng  = (const float*)d_in[33]; const float* nb  = (const float*)d_in[34];

    float* ws = (float*)d_ws;
    float* xA   = ws;
    float* xB   = xA  + (size_t)ROWS * DDIM;
    float* xn   = xB  + (size_t)ROWS * DDIM;
    float* xp   = xn  + (size_t)ROWS * DDIM;
    float* zb   = xp  + (size_t)ROWS * EDIM;
    float* xfb  = zb  + (size_t)ROWS * EDIM;
    float* xbb  = xfb + (size_t)ROWS * EDIM;
    float* yfb  = xbb + (size_t)ROWS * EDIM;
    float* ybb  = yfb + (size_t)ROWS * EDIM;
    float* ycb  = ybb + (size_t)ROWS * EDIM;
    float* dlt  = ycb + (size_t)ROWS * EDIM;
    float* dlt2 = dlt + (size_t)ROWS * EDIM;
    float* Bmb  = dlt2 + (size_t)ROWS * EDIM;         // ROWS*ENDIM
    float* Cmb  = Bmb + (size_t)ROWS * ENDIM;
    // patchify scratch aliases the (not-yet-needed) B buffer
    float* patches = Bmb;                             // PROWS*PATCH_K
    float* xemb    = Bmb + (size_t)PROWS * PATCH_K;   // PROWS*DDIM

    // --- patch embedding ---
    patchify_k<<<(PROWS * PATCH_K + 255) / 256, 256, 0, stream>>>(img, patches);
    {   // 1568x192x768 GEMM
        dim3 g(DDIM / 32, (PROWS + 31) / 32, 1);
        gemm_s<false, false, false><<<g, 64, 0, stream>>>(
            patches, patch_w, patch_b, nullptr, nullptr, xemb,
            patches, patch_w, patch_b, nullptr, nullptr, xemb,
            PROWS, DDIM, PATCH_K);
    }
    assemble_k<<<(ROWS * DDIM + 255) / 256, 256, 0, stream>>>(xemb, cls, pos, xA);

    float* cur = xA; float* nxt = xB;
    for (int i = 0; i < LLAYERS; ++i) {
        layernorm_k<<<(ROWS + 3) / 4, 256, 0, stream>>>(cur, ln_g + i * DDIM, ln_b + i * DDIM, xn, ROWS);
        {   // Wx + Wz fused (shared A=xn)
            dim3 g(EDIM / 32, (ROWS + 31) / 32, 2);
            gemm_s<false, false, false><<<g, 64, 0, stream>>>(
                xn, Wx + (size_t)i * DDIM * EDIM, bx + i * EDIM, nullptr, nullptr, xp,
                xn, Wz + (size_t)i * DDIM * EDIM, bz + i * EDIM, nullptr, nullptr, zb,
                ROWS, EDIM, DDIM);
        }
        dwconv_k<<<(ROWS * EDIM + 255) / 256, 256, 0, stream>>>(xp, cwf + i * EDIM * 3, cbf + i * EDIM,
                                                                cwb + i * EDIM * 3, cbb + i * EDIM, xfb, xbb);
        {   // Df + Db fused (CR softplus epilogue)
            dim3 g(EDIM / 32, (ROWS + 31) / 32, 2);
            gemm_s<true, true, false><<<g, 64, 0, stream>>>(
                xfb, WDf + (size_t)i * EDIM * EDIM, bDf + i * EDIM, dbf + i * EDIM, nullptr, dlt,
                xbb, WDb + (size_t)i * EDIM * EDIM, bDb + i * EDIM, dbb + i * EDIM, nullptr, dlt2,
                ROWS, EDIM, EDIM);
        }
        {   // Bf + Cf fused z=2 (shared A=xfb; W set 18.8MB = L2-resident)
            dim3 g(ENDIM / 128, (ROWS + BM - 1) / BM, 2);
            gemm_big<<<g, 256, 0, stream>>>(
                xfb,
                WBf + (size_t)i * EDIM * ENDIM, bBf + i * ENDIM, Bmb,
                WCf + (size_t)i * EDIM * ENDIM, bCf + i * ENDIM, Cmb,
                ROWS, ENDIM, EDIM);
        }
        ssm_scan_k<<<BATCH * EDIM, 256, 0, stream>>>(Bmb, Cmb, dlt, xfb, Af + i * EDIM * NSTATE,
                                                     yfb, nullptr, nullptr, nullptr);
        {   // Bb + Cb fused z=2 (shared A=xbb)
            dim3 g(ENDIM / 128, (ROWS + BM - 1) / BM, 2);
            gemm_big<<<g, 256, 0, stream>>>(
                xbb,
                WBb + (size_t)i * EDIM * ENDIM, bBb + i * ENDIM, Bmb,
                WCb + (size_t)i * EDIM * ENDIM, bCb + i * ENDIM, Cmb,
                ROWS, ENDIM, EDIM);
        }
        // bwd scan with FUSED combine: ycb = (yfb + y_b) * silu(zb)
        ssm_scan_k<<<BATCH * EDIM, 256, 0, stream>>>(Bmb, Cmb, dlt2, xbb, Ab + i * EDIM * NSTATE,
                                                     ybb, yfb, zb, ycb);
        {   // Wout with residual
            dim3 g(DDIM / 32, (ROWS + 31) / 32, 1);
            gemm_s<false, false, true><<<g, 64, 0, stream>>>(
                ycb, Wout + (size_t)i * EDIM * DDIM, bout + i * DDIM, nullptr, cur, nxt,
                ycb, Wout + (size_t)i * EDIM * DDIM, bout + i * DDIM, nullptr, cur, nxt,
                ROWS, DDIM, EDIM);
        }
        float* t = cur; cur = nxt; nxt = t;
    }
    layernorm_k<<<(ROWS + 3) / 4, 256, 0, stream>>>(cur, ng, nb, (float*)d_out, ROWS);
}

// Round 13
// 1115.212 us; speedup vs baseline: 1.1875x; 1.0755x over previous
//
#include <hip/hip_runtime.h>
#include <hip/hip_bf16.h>
#include <math.h>

// ---- problem constants ----
#define BATCH   8
#define C_IN    3
#define IMG_SZ  224
#define P_SZ    16
#define NPATCH  196                 // (224/16)^2
#define MSEQ    197                 // NPATCH + cls
#define DDIM    192
#define EDIM    384
#define NSTATE  16
#define ENDIM   (EDIM*NSTATE)       // 6144
#define LLAYERS 2
#define ROWS    (BATCH*MSEQ)        // 1576
#define PROWS   (BATCH*NPATCH)      // 1568
#define PATCH_K (C_IN*P_SZ*P_SZ)    // 768
#define AP_ROWS 1664                // 13*128, padded M for MFMA tiles

typedef unsigned short u16;
typedef __attribute__((ext_vector_type(8))) short bf16x8;
typedef __attribute__((ext_vector_type(16))) float f32x16;

// precise silu (enters the scan only linearly)
__device__ __forceinline__ float silu_f(float x) { return x / (1.f + expf(-x)); }

// RNE fp32 -> bf16 (bit-level, no library dependence)
__device__ __forceinline__ u16 f2bf(float f) {
    unsigned u = __float_as_uint(f);
    unsigned r = (u + 0x7FFFu + ((u >> 16) & 1u)) >> 16;
    return (u16)r;
}
__device__ __forceinline__ float bf2f(u16 h) {
    return __uint_as_float(((unsigned)h) << 16);
}

// ------------------------------------------------------------------
// patchify: img (B,3,224,224) -> patches (PROWS, 768)
// ------------------------------------------------------------------
__global__ __launch_bounds__(256) void patchify_k(const float* __restrict__ img,
                                                  float* __restrict__ out) {
    int idx = blockIdx.x * 256 + threadIdx.x;
    if (idx >= PROWS * PATCH_K) return;
    int r = idx / PATCH_K, col = idx - r * PATCH_K;
    int b = r / NPATCH, p = r - b * NPATCH;
    int ph = p / 14, pw = p - ph * 14;
    int c = col >> 8, rem = col & 255, py = rem >> 4, px = rem & 15;
    out[idx] = img[((b * C_IN + c) * IMG_SZ + ph * P_SZ + py) * IMG_SZ + pw * P_SZ + px];
}

// ------------------------------------------------------------------
// assemble x = concat(cls, xemb) + pos   -> (B, MSEQ, DDIM)
// ------------------------------------------------------------------
__global__ __launch_bounds__(256) void assemble_k(const float* __restrict__ xemb,
                                                  const float* __restrict__ cls,
                                                  const float* __restrict__ pos,
                                                  float* __restrict__ x) {
    int idx = blockIdx.x * 256 + threadIdx.x;
    if (idx >= ROWS * DDIM) return;
    int d = idx % DDIM;
    int bm = idx / DDIM;
    int m = bm % MSEQ, b = bm / MSEQ;
    float v;
    if (m == 0) v = cls[d];
    else        v = xemb[((b * NPATCH) + (m - 1)) * DDIM + d];
    x[idx] = v + pos[m * DDIM + d];
}

// ------------------------------------------------------------------
// layernorm over last dim (DDIM=192), one wave per row
// ------------------------------------------------------------------
__global__ __launch_bounds__(256) void layernorm_k(const float* __restrict__ x,
                                                   const float* __restrict__ g,
                                                   const float* __restrict__ b,
                                                   float* __restrict__ o, int nrows) {
    int wave = threadIdx.x >> 6;
    int lane = threadIdx.x & 63;
    int row = blockIdx.x * 4 + wave;
    if (row >= nrows) return;
    const float* xr = x + (long)row * DDIM;
    float v0 = xr[lane], v1 = xr[lane + 64], v2 = xr[lane + 128];
    float s = v0 + v1 + v2;
    #pragma unroll
    for (int off = 1; off < 64; off <<= 1) s += __shfl_xor(s, off);
    float mu = s * (1.f / 192.f);
    float d0 = v0 - mu, d1 = v1 - mu, d2 = v2 - mu;
    float q = d0 * d0 + d1 * d1 + d2 * d2;
    #pragma unroll
    for (int off = 1; off < 64; off <<= 1) q += __shfl_xor(q, off);
    float inv = rsqrtf(q * (1.f / 192.f) + 1e-5f);
    float* orow = o + (long)row * DDIM;
    orow[lane]       = d0 * inv * g[lane]       + b[lane];
    orow[lane + 64]  = d1 * inv * g[lane + 64]  + b[lane + 64];
    orow[lane + 128] = d2 * inv * g[lane + 128] + b[lane + 128];
}

// ------------------------------------------------------------------
// convA: split xf/xb (ROWS x EDIM fp32) into 3 exact bf16 planes each:
// x = hi + mid + lo (24 = 3x8 mantissa bits; split is exact).
// Output layout [3][AP_ROWS][EDIM]; padded rows stay untouched
// (deterministic garbage, results discarded by the GEMM epilogue).
// ------------------------------------------------------------------
__global__ __launch_bounds__(256) void convA_k(const float* __restrict__ xf,
                                               const float* __restrict__ xb,
                                               u16* __restrict__ Af3,
                                               u16* __restrict__ Ab3) {
    int idx = blockIdx.x * 256 + threadIdx.x;
    if (idx >= ROWS * EDIM) return;
    int row = idx / EDIM, k = idx - row * EDIM;
    long base = (long)row * EDIM + k;
    #pragma unroll
    for (int s = 0; s < 2; ++s) {
        float x = s ? xb[idx] : xf[idx];
        u16* out = s ? Ab3 : Af3;
        u16 hb = f2bf(x);        float fh = bf2f(hb);
        float r1 = x - fh;
        u16 mb = f2bf(r1);       float fm = bf2f(mb);
        u16 lb = f2bf(r1 - fm);
        out[base] = hb;
        out[(long)AP_ROWS * EDIM + base] = mb;
        out[2L * AP_ROWS * EDIM + base] = lb;
    }
}

// ------------------------------------------------------------------
// convWt: W (K=384 x N=6144 fp32) -> Wt 3 bf16 planes TRANSPOSED
// [3][N][K] (k-contiguous, as the MFMA B-frag wants). Tiled 64x64
// transpose through LDS; z in {0..3} selects {WBf,WCf,WBb,WCb}.
// ------------------------------------------------------------------
__global__ __launch_bounds__(256) void convWt_k(const float* __restrict__ W0,
                                                const float* __restrict__ W1,
                                                const float* __restrict__ W2,
                                                const float* __restrict__ W3,
                                                u16* __restrict__ Wt) {
    int z = blockIdx.z;
    const float* W = (z == 0) ? W0 : (z == 1) ? W1 : (z == 2) ? W2 : W3;
    u16* out = Wt + (long)z * 3L * ENDIM * EDIM;
    __shared__ float tile[64][65];
    int n0 = blockIdx.x * 64, k0 = blockIdx.y * 64;
    int t = threadIdx.x;
    #pragma unroll
    for (int i = 0; i < 16; ++i) {
        int id = t + 256 * i;
        int kk = id >> 6, nn = id & 63;
        tile[kk][nn] = W[(long)(k0 + kk) * ENDIM + n0 + nn];
    }
    __syncthreads();
    #pragma unroll
    for (int i = 0; i < 2; ++i) {
        int id = t + 256 * i;
        int nn = id >> 3, ch = id & 7;
        uint4 hq, mq, lq;
        u16* hp = (u16*)&hq; u16* mp = (u16*)&mq; u16* lp = (u16*)&lq;
        #pragma unroll
        for (int j = 0; j < 8; ++j) {
            float x = tile[ch * 8 + j][nn];
            u16 hb = f2bf(x);        float fh = bf2f(hb);
            float r1 = x - fh;
            u16 mb = f2bf(r1);       float fm = bf2f(mb);
            u16 lb = f2bf(r1 - fm);
            hp[j] = hb; mp[j] = mb; lp[j] = lb;
        }
        long rowoff = (long)(n0 + nn) * EDIM + k0 + ch * 8;
        *(uint4*)&out[rowoff] = hq;
        *(uint4*)&out[(long)ENDIM * EDIM + rowoff] = mq;
        *(uint4*)&out[2L * ENDIM * EDIM + rowoff] = lq;
    }
}

// ------------------------------------------------------------------
// MFMA GEMM for B/C projections: C[M,N] = A[M,K] @ W[K,N] + bias,
// computed as a 6-term bf16x3-split (hi*Hi, hi*Mid, mid*Hi, hi*Lo,
// lo*Hi, mid*Mid) with fp32 MFMA accumulation — ~fp32-accurate.
// Tile 128x128, 4 waves (2x2 of 64x64), v_mfma_f32_32x32x16_bf16.
// A planes staged in LDS (padded rows, immediate-stage: L2 lockstep
// discipline from r9/r10); W frags read DIRECT from global Wt[N][K]
// (L2-resident, bypasses the LDS pipe that capped the fp32 kernel).
// Fragment layouts: A row=l&31,k=(l>>5)*8+j; B col=l&31, same k;
// C/D col=lane&31,row=(reg&3)+8*(reg>>2)+4*(lane>>5) [m74/m101].
// gridDim.z=2 shares A across the {B,C} pair.
// ------------------------------------------------------------------
__global__ __launch_bounds__(256) void gemm_mfma(
        const u16* __restrict__ A3,                      // [3][AP_ROWS][384]
        const u16* __restrict__ Wt0, const float* __restrict__ b0, float* __restrict__ C0,
        const u16* __restrict__ Wt1, const float* __restrict__ b1, float* __restrict__ C1) {
    const u16* Wt    = blockIdx.z ? Wt1 : Wt0;
    const float* bias = blockIdx.z ? b1 : b0;
    float* C          = blockIdx.z ? C1 : C0;
    __shared__ u16 As[3][128][40];                       // pad k 32->40 (80B rows)
    int t = threadIdx.x;
    int lane = t & 63, wv = t >> 6;
    int wr = wv >> 1, wc = wv & 1;
    int l31 = lane & 31, l5 = lane >> 5;
    int rowBase = blockIdx.y * 128;
    long colBase = (long)blockIdx.x * 128;
    f32x16 acc[2][2] = {};

    for (int k0 = 0; k0 < EDIM; k0 += 32) {
        // stage A planes (16B chunks, coalesced; immediate-stage)
        #pragma unroll
        for (int i = 0; i < 6; ++i) {
            int id = t + 256 * i;
            int p = id >> 9, rem = id & 511, row = rem >> 2, ch = rem & 3;
            const u16* src = A3 + ((long)p * AP_ROWS + rowBase + row) * EDIM + k0 + ch * 8;
            uint4 v = *(const uint4*)src;
            *(uint4*)&As[p][row][ch * 8] = v;
        }
        __syncthreads();
        // load all frags for both K=16 halves, then MFMA
        bf16x8 af[2][2][3], wf[2][2][3];
        #pragma unroll
        for (int ks = 0; ks < 2; ++ks) {
            #pragma unroll
            for (int r = 0; r < 2; ++r)
                #pragma unroll
                for (int p = 0; p < 3; ++p)
                    af[ks][r][p] = *(const bf16x8*)&As[p][wr * 64 + r * 32 + l31][ks * 16 + l5 * 8];
            #pragma unroll
            for (int c = 0; c < 2; ++c)
                #pragma unroll
                for (int p = 0; p < 3; ++p)
                    wf[ks][c][p] = *(const bf16x8*)&Wt[((long)p * ENDIM + colBase + wc * 64 + c * 32 + l31) * EDIM
                                                      + k0 + ks * 16 + l5 * 8];
        }
        #pragma unroll
        for (int ks = 0; ks < 2; ++ks)
            #pragma unroll
            for (int r = 0; r < 2; ++r)
                #pragma unroll
                for (int c = 0; c < 2; ++c) {
                    f32x16 d = acc[r][c];
                    d = __builtin_amdgcn_mfma_f32_32x32x16_bf16(af[ks][r][0], wf[ks][c][0], d, 0, 0, 0);
                    d = __builtin_amdgcn_mfma_f32_32x32x16_bf16(af[ks][r][0], wf[ks][c][1], d, 0, 0, 0);
                    d = __builtin_amdgcn_mfma_f32_32x32x16_bf16(af[ks][r][1], wf[ks][c][0], d, 0, 0, 0);
                    d = __builtin_amdgcn_mfma_f32_32x32x16_bf16(af[ks][r][0], wf[ks][c][2], d, 0, 0, 0);
                    d = __builtin_amdgcn_mfma_f32_32x32x16_bf16(af[ks][r][2], wf[ks][c][0], d, 0, 0, 0);
                    d = __builtin_amdgcn_mfma_f32_32x32x16_bf16(af[ks][r][1], wf[ks][c][1], d, 0, 0, 0);
                    acc[r][c] = d;
                }
        __syncthreads();
    }
    // epilogue: C/D layout col=lane&31, row=(reg&3)+8*(reg>>2)+4*(lane>>5)
    #pragma unroll
    for (int r = 0; r < 2; ++r) {
        int rb = rowBase + wr * 64 + r * 32 + 4 * l5;
        #pragma unroll
        for (int c = 0; c < 2; ++c) {
            long cb = colBase + wc * 64 + c * 32 + l31;
            float bv = bias[cb];
            #pragma unroll
            for (int i = 0; i < 16; ++i) {
                int rr = rb + (i & 3) + 8 * (i >> 2);
                if (rr < ROWS) C[(long)rr * ENDIM + cb] = acc[r][c][i] + bv;
            }
        }
    }
}

// ------------------------------------------------------------------
// SMALL fp32 GEMM: one WAVE per 32x32 tile, 4x4/thread, double-
// buffered LDS. gridDim.z selects two independent sets (Wx+Wz, Df+Db).
// SP = correctly-rounded softplus epilogue. k-ascending FMA order
// (Delta path must stay bit-exact: P-trajectory depends on it).
// ------------------------------------------------------------------
#define SBK 16
template<bool SP, bool HASB2, bool HASRES>
__global__ __launch_bounds__(64) void gemm_s(const float* __restrict__ A0,
                                             const float* __restrict__ W0,
                                             const float* __restrict__ b10,
                                             const float* __restrict__ b20,
                                             const float* __restrict__ r0,
                                             float* __restrict__ C0,
                                             const float* __restrict__ A1,
                                             const float* __restrict__ W1,
                                             const float* __restrict__ b11,
                                             const float* __restrict__ b21,
                                             const float* __restrict__ r1,
                                             float* __restrict__ C1,
                                             int M, int N, int K) {
    const float* A  = blockIdx.z ? A1  : A0;
    const float* W  = blockIdx.z ? W1  : W0;
    const float* bp = blockIdx.z ? b11 : b10;
    const float* b2 = blockIdx.z ? b21 : b20;
    const float* rp = blockIdx.z ? r1  : r0;
    float*       C  = blockIdx.z ? C1  : C0;
    __shared__ float As[2][SBK][36];
    __shared__ float Wsh[2][SBK][36];
    int t = threadIdx.x;            // 0..63
    int tx = t & 7, ty = t >> 3;
    int rowBase = blockIdx.y * 32;
    long colBase = (long)blockIdx.x * 32;
    int rA = t >> 2, kqA = (t & 3) << 2;
    int kW = t >> 3, nqW = (t & 7) << 2;
    float acc[4][4] = {};
    int r0i = rowBase + rA, r1i = r0i + 16;

    auto loadA = [&](int k0, float4& a0, float4& a1) {
        a0 = make_float4(0.f,0.f,0.f,0.f); a1 = a0;
        if (r0i < M) a0 = *(const float4*)&A[(long)r0i * K + k0 + kqA];
        if (r1i < M) a1 = *(const float4*)&A[(long)r1i * K + k0 + kqA];
    };
    auto stage = [&](int buf, float4 a0, float4 a1, float4 w0, float4 w1) {
        As[buf][kqA + 0][rA] = a0.x; As[buf][kqA + 1][rA] = a0.y;
        As[buf][kqA + 2][rA] = a0.z; As[buf][kqA + 3][rA] = a0.w;
        As[buf][kqA + 0][rA + 16] = a1.x; As[buf][kqA + 1][rA + 16] = a1.y;
        As[buf][kqA + 2][rA + 16] = a1.z; As[buf][kqA + 3][rA + 16] = a1.w;
        *(float4*)&Wsh[buf][kW][nqW]     = w0;
        *(float4*)&Wsh[buf][kW + 8][nqW] = w1;
    };
    auto compute = [&](int buf) {
        #pragma unroll
        for (int kk = 0; kk < SBK; ++kk) {
            float4 av = *(const float4*)&As[buf][kk][ty << 2];
            float4 wv = *(const float4*)&Wsh[buf][kk][tx << 2];
            float ar[4] = {av.x, av.y, av.z, av.w};
            float wr[4] = {wv.x, wv.y, wv.z, wv.w};
            #pragma unroll
            for (int i = 0; i < 4; ++i)
                #pragma unroll
                for (int j = 0; j < 4; ++j) acc[i][j] += ar[i] * wr[j];
        }
    };

    {
        float4 a0, a1;
        loadA(0, a0, a1);
        float4 w0 = *(const float4*)&W[(long)kW * N + colBase + nqW];
        float4 w1 = *(const float4*)&W[(long)(kW + 8) * N + colBase + nqW];
        stage(0, a0, a1, w0, w1);
    }
    __syncthreads();
    int cur = 0;
    int nt = K / SBK;
    for (int kt = 1; kt < nt; ++kt) {
        int k0 = kt * SBK;
        float4 a0, a1;
        loadA(k0, a0, a1);
        float4 w0 = *(const float4*)&W[(long)(k0 + kW) * N + colBase + nqW];
        float4 w1 = *(const float4*)&W[(long)(k0 + kW + 8) * N + colBase + nqW];
        compute(cur);
        stage(cur ^ 1, a0, a1, w0, w1);
        __syncthreads();
        cur ^= 1;
    }
    compute(cur);

    #pragma unroll
    for (int i = 0; i < 4; ++i) {
        int r = rowBase + (ty << 2) + i;
        if (r >= M) break;
        long cb = colBase + (tx << 2);
        float vv[4];
        #pragma unroll
        for (int j = 0; j < 4; ++j) {
            float v = acc[i][j] + bp[cb + j];
            if (HASB2) v += b2[cb + j];
            if (SP) {  // correctly-rounded fp32 softplus via fp64
                double vd = (double)v;
                v = (float)(log1p(exp(-fabs(vd))) + fmax(vd, 0.0));
            }
            if (HASRES) v += rp[(long)r * N + cb + j];
            vv[j] = v;
        }
        float4 o; o.x = vv[0]; o.y = vv[1]; o.z = vv[2]; o.w = vv[3];
        *(float4*)&C[(long)r * N + cb] = o;
    }
}

// ------------------------------------------------------------------
// fused depthwise conv (fwd + bwd) + SiLU
// ------------------------------------------------------------------
__global__ __launch_bounds__(256) void dwconv_k(const float* __restrict__ xp,
                                                const float* __restrict__ wf,
                                                const float* __restrict__ bf,
                                                const float* __restrict__ wb,
                                                const float* __restrict__ bb,
                                                float* __restrict__ xf,
                                                float* __restrict__ xb) {
    int idx = blockIdx.x * 256 + threadIdx.x;
    if (idx >= ROWS * EDIM) return;
    int e = idx % EDIM;
    int bm = idx / EDIM;
    int m = bm % MSEQ, b = bm / MSEQ;
    const float* base = xp + (long)b * MSEQ * EDIM + e;
    float xm1 = (m > 0)        ? base[(m - 1) * EDIM] : 0.f;
    float x0  =                  base[m * EDIM];
    float xp1 = (m < MSEQ - 1) ? base[(m + 1) * EDIM] : 0.f;
    float f = wf[e * 3 + 0] * xm1 + wf[e * 3 + 1] * x0 + wf[e * 3 + 2] * xp1 + bf[e];
    float r = wb[e * 3 + 0] * xp1 + wb[e * 3 + 1] * x0 + wb[e * 3 + 2] * xm1 + bb[e];
    xf[idx] = silu_f(f);
    xb[idx] = silu_f(r);
}

// ------------------------------------------------------------------
// SSM recurrence, PHASE-PARALLEL, bit-exact fp32 chains; CR fp64
// transcendentals. One block per (b,e). ycomb!=nullptr fuses combine.
// ------------------------------------------------------------------
__global__ __launch_bounds__(256) void ssm_scan_k(const float* __restrict__ Bm,
                                                  const float* __restrict__ Cm,
                                                  const float* __restrict__ Dlt,
                                                  const float* __restrict__ xs,
                                                  const float* __restrict__ Apar,
                                                  float* __restrict__ y,
                                                  const float* __restrict__ yother,
                                                  const float* __restrict__ zg,
                                                  float* __restrict__ ycomb) {
#pragma clang fp contract(off)
    __shared__ float lgP[MSEQ][17];
    __shared__ float trm[MSEQ][17];
    __shared__ signed char sgn[MSEQ][17];
    int be = blockIdx.x;
    int b = be / EDIM, e = be - b * EDIM;
    int t = threadIdx.x;
    int n0 = t & 15;
    float Ap = Apar[e * NSTATE + n0];
    const long dxBase = (long)b * MSEQ * EDIM + e;
    const long bcBase = (long)b * MSEQ * ENDIM + e * NSTATE;

    for (int idx = t; idx < MSEQ * NSTATE; idx += 256) {
        int m = idx >> 4;
        float delta = Dlt[dxBase + (long)m * EDIM];
        float A = delta * Ap;
        float sa = (A > 0.f) ? 1.f : ((A < 0.f) ? -1.f : 0.f);
        float absA = fmaxf(fabsf(A), 1e-6f);
        lgP[m][n0] = (float)log((double)absA);
        sgn[m][n0] = (signed char)sa;
    }
    __syncthreads();
    if (t < NSTATE) {
        float cl = 0.f, cs = 1.f;
        for (int m = 0; m < MSEQ; ++m) {
            float sa = (float)sgn[m][t];
            cs = cs * sa;
            cl = cl + lgP[m][t];
            lgP[m][t] = cl;
            sgn[m][t] = (signed char)cs;
        }
    }
    __syncthreads();
    for (int idx = t; idx < MSEQ * NSTATE; idx += 256) {
        int m = idx >> 4;
        float cl = lgP[m][n0];
        float cs = (float)sgn[m][n0];
        float ex = (float)exp((double)cl);
        float P = cs * ex;
        float tt = P + 1e-6f;
        float invP = 1.0f / tt;
        float delta = Dlt[dxBase + (long)m * EDIM];
        float xv = xs[dxBase + (long)m * EDIM];
        float Bv = Bm[bcBase + (long)m * ENDIM + n0];
        float Bfull = delta * Bv;
        float t1 = invP * Bfull;
        float t2 = t1 * xv;
        trm[m][n0] = t2;
        lgP[m][n0] = P;
    }
    __syncthreads();
    if (t < NSTATE) {
        float S = 0.f;
        for (int m = 0; m < MSEQ; ++m) {
            S = S + trm[m][t];
            float h = lgP[m][t] * S;
            trm[m][t] = h;
        }
    }
    __syncthreads();
    for (int m = t; m < MSEQ; m += 256) {
        const float* cp = &Cm[bcBase + (long)m * ENDIM];
        float a[16];
        #pragma unroll
        for (int n = 0; n < 16; ++n) a[n] = trm[m][n] * cp[n];
        float b0 = a[0] + a[8],  b1 = a[1] + a[9];
        float b2v = a[2] + a[10], b3 = a[3] + a[11];
        float b4 = a[4] + a[12], b5 = a[5] + a[13];
        float b6 = a[6] + a[14], b7 = a[7] + a[15];
        float c0 = b0 + b1, c2 = b2v + b3, c4 = b4 + b5, c6 = b6 + b7;
        float d0 = c0 + c2, d4 = c4 + c6;
        float val = d0 + d4;
        long o = dxBase + (long)m * EDIM;
        if (ycomb) ycomb[o] = (yother[o] + val) * silu_f(zg[o]);
        else       y[o] = val;
    }
}

extern "C" void kernel_launch(void* const* d_in, const int* in_sizes, int n_in,
                              void* d_out, int out_size, void* d_ws, size_t ws_size,
                              hipStream_t stream) {
    const float* img     = (const float*)d_in[0];
    const float* patch_w = (const float*)d_in[1];
    const float* patch_b = (const float*)d_in[2];
    const float* cls     = (const float*)d_in[3];
    const float* pos     = (const float*)d_in[4];
    const float* ln_g    = (const float*)d_in[5];
    const float* ln_b    = (const float*)d_in[6];
    const float* Wx  = (const float*)d_in[7];  const float* bx  = (const float*)d_in[8];
    const float* Wz  = (const float*)d_in[9];  const float* bz  = (const float*)d_in[10];
    const float* cwf = (const float*)d_in[11]; const float* cbf = (const float*)d_in[12];
    const float* cwb = (const float*)d_in[13]; const float* cbb = (const float*)d_in[14];
    const float* WBf = (const float*)d_in[15]; const float* bBf = (const float*)d_in[16];
    const float* WCf = (const float*)d_in[17]; const float* bCf = (const float*)d_in[18];
    const float* WDf = (const float*)d_in[19]; const float* bDf = (const float*)d_in[20];
    const float* Af  = (const float*)d_in[21]; const float* dbf = (const float*)d_in[22];
    const float* WBb = (const float*)d_in[23]; const float* bBb = (const float*)d_in[24];
    const float* WCb = (const float*)d_in[25]; const float* bCb = (const float*)d_in[26];
    const float* WDb = (const float*)d_in[27]; const float* bDb = (const float*)d_in[28];
    const float* Ab  = (const float*)d_in[29]; const float* dbb = (const float*)d_in[30];
    const float* Wout= (const float*)d_in[31]; const float* bout= (const float*)d_in[32];
    const float* ng  = (const float*)d_in[33]; const float* nb  = (const float*)d_in[34];

    float* ws = (float*)d_ws;
    float* xA   = ws;
    float* xB   = xA  + (size_t)ROWS * DDIM;
    float* xn   = xB  + (size_t)ROWS * DDIM;
    float* xp   = xn  + (size_t)ROWS * DDIM;
    float* zb   = xp  + (size_t)ROWS * EDIM;
    float* xfb  = zb  + (size_t)ROWS * EDIM;
    float* xbb  = xfb + (size_t)ROWS * EDIM;
    float* yfb  = xbb + (size_t)ROWS * EDIM;
    float* ybb  = yfb + (size_t)ROWS * EDIM;
    float* ycb  = ybb + (size_t)ROWS * EDIM;
    float* dlt  = ycb + (size_t)ROWS * EDIM;
    float* dlt2 = dlt + (size_t)ROWS * EDIM;
    float* Bmb  = dlt2 + (size_t)ROWS * EDIM;         // ROWS*ENDIM
    float* Cmb  = Bmb + (size_t)ROWS * ENDIM;
    u16*   Af3  = (u16*)(Cmb + (size_t)ROWS * ENDIM); // [3][AP_ROWS][EDIM]
    u16*   Ab3  = Af3 + 3L * AP_ROWS * EDIM;
    u16*   Wt4  = Ab3 + 3L * AP_ROWS * EDIM;          // [4][3][ENDIM][EDIM]
    // patchify scratch aliases the (not-yet-needed) B buffer
    float* patches = Bmb;                             // PROWS*PATCH_K
    float* xemb    = Bmb + (size_t)PROWS * PATCH_K;   // PROWS*DDIM

    const long WtSz = 3L * ENDIM * EDIM;              // u16 per converted matrix

    // --- patch embedding ---
    patchify_k<<<(PROWS * PATCH_K + 255) / 256, 256, 0, stream>>>(img, patches);
    {   // 1568x192x768 GEMM
        dim3 g(DDIM / 32, (PROWS + 31) / 32, 1);
        gemm_s<false, false, false><<<g, 64, 0, stream>>>(
            patches, patch_w, patch_b, nullptr, nullptr, xemb,
            patches, patch_w, patch_b, nullptr, nullptr, xemb,
            PROWS, DDIM, PATCH_K);
    }
    assemble_k<<<(ROWS * DDIM + 255) / 256, 256, 0, stream>>>(xemb, cls, pos, xA);

    float* cur = xA; float* nxt = xB;
    for (int i = 0; i < LLAYERS; ++i) {
        layernorm_k<<<(ROWS + 3) / 4, 256, 0, stream>>>(cur, ln_g + i * DDIM, ln_b + i * DDIM, xn, ROWS);
        {   // Wx + Wz fused (shared A=xn)
            dim3 g(EDIM / 32, (ROWS + 31) / 32, 2);
            gemm_s<false, false, false><<<g, 64, 0, stream>>>(
                xn, Wx + (size_t)i * DDIM * EDIM, bx + i * EDIM, nullptr, nullptr, xp,
                xn, Wz + (size_t)i * DDIM * EDIM, bz + i * EDIM, nullptr, nullptr, zb,
                ROWS, EDIM, DDIM);
        }
        dwconv_k<<<(ROWS * EDIM + 255) / 256, 256, 0, stream>>>(xp, cwf + i * EDIM * 3, cbf + i * EDIM,
                                                                cwb + i * EDIM * 3, cbb + i * EDIM, xfb, xbb);
        convA_k<<<(ROWS * EDIM + 255) / 256, 256, 0, stream>>>(xfb, xbb, Af3, Ab3);
        {   // Df + Db fused (CR softplus epilogue) — fp32 path, P stays bit-exact
            dim3 g(EDIM / 32, (ROWS + 31) / 32, 2);
            gemm_s<true, true, false><<<g, 64, 0, stream>>>(
                xfb, WDf + (size_t)i * EDIM * EDIM, bDf + i * EDIM, dbf + i * EDIM, nullptr, dlt,
                xbb, WDb + (size_t)i * EDIM * EDIM, bDb + i * EDIM, dbb + i * EDIM, nullptr, dlt2,
                ROWS, EDIM, EDIM);
        }
        {   // convert the 4 big weight matrices -> transposed bf16x3 planes
            dim3 g(ENDIM / 64, EDIM / 64, 4);
            convWt_k<<<g, 256, 0, stream>>>(
                WBf + (size_t)i * EDIM * ENDIM, WCf + (size_t)i * EDIM * ENDIM,
                WBb + (size_t)i * EDIM * ENDIM, WCb + (size_t)i * EDIM * ENDIM, Wt4);
        }
        {   // Bf + Cf via MFMA (shared A planes)
            dim3 g(ENDIM / 128, AP_ROWS / 128, 2);
            gemm_mfma<<<g, 256, 0, stream>>>(
                Af3,
                Wt4 + 0 * WtSz, bBf + i * ENDIM, Bmb,
                Wt4 + 1 * WtSz, bCf + i * ENDIM, Cmb);
        }
        ssm_scan_k<<<BATCH * EDIM, 256, 0, stream>>>(Bmb, Cmb, dlt, xfb, Af + i * EDIM * NSTATE,
                                                     yfb, nullptr, nullptr, nullptr);
        {   // Bb + Cb via MFMA
            dim3 g(ENDIM / 128, AP_ROWS / 128, 2);
            gemm_mfma<<<g, 256, 0, stream>>>(
                Ab3,
                Wt4 + 2 * WtSz, bBb + i * ENDIM, Bmb,
                Wt4 + 3 * WtSz, bCb + i * ENDIM, Cmb);
        }
        // bwd scan with FUSED combine: ycb = (yfb + y_b) * silu(zb)
        ssm_scan_k<<<BATCH * EDIM, 256, 0, stream>>>(Bmb, Cmb, dlt2, xbb, Ab + i * EDIM * NSTATE,
                                                     ybb, yfb, zb, ycb);
        {   // Wout with residual
            dim3 g(DDIM / 32, (ROWS + 31) / 32, 1);
            gemm_s<false, false, true><<<g, 64, 0, stream>>>(
                ycb, Wout + (size_t)i * EDIM * DDIM, bout + i * DDIM, nullptr, cur, nxt,
                ycb, Wout + (size_t)i * EDIM * DDIM, bout + i * DDIM, nullptr, cur, nxt,
                ROWS, DDIM, EDIM);
        }
        float* t = cur; cur = nxt; nxt = t;
    }
    layernorm_k<<<(ROWS + 3) / 4, 256, 0, stream>>>(cur, ng, nb, (float*)d_out, ROWS);
}

// Round 14
// 932.977 us; speedup vs baseline: 1.4194x; 1.1953x over previous
//
#include <hip/hip_runtime.h>
#include <hip/hip_bf16.h>
#include <math.h>

// ---- problem constants ----
#define BATCH   8
#define C_IN    3
#define IMG_SZ  224
#define P_SZ    16
#define NPATCH  196                 // (224/16)^2
#define MSEQ    197                 // NPATCH + cls
#define DDIM    192
#define EDIM    384
#define NSTATE  16
#define ENDIM   (EDIM*NSTATE)       // 6144
#define LLAYERS 2
#define ROWS    (BATCH*MSEQ)        // 1576
#define PROWS   (BATCH*NPATCH)      // 1568
#define PATCH_K (C_IN*P_SZ*P_SZ)    // 768
#define AP_ROWS 1664                // 13*128, padded M for MFMA tiles
#define MFRAGS  52                  // AP_ROWS/32
#define NFRAGS  192                 // ENDIM/32
#define KBLKS   24                  // EDIM/16
#define FRAG    512                 // u16 per fragment (64 lanes x 8)

typedef unsigned short u16;
typedef __attribute__((ext_vector_type(8))) short bf16x8;
typedef __attribute__((ext_vector_type(16))) float f32x16;

// precise silu (enters the scan only linearly)
__device__ __forceinline__ float silu_f(float x) { return x / (1.f + expf(-x)); }

// RNE fp32 -> bf16 (bit-level)
__device__ __forceinline__ u16 f2bf(float f) {
    unsigned u = __float_as_uint(f);
    unsigned r = (u + 0x7FFFu + ((u >> 16) & 1u)) >> 16;
    return (u16)r;
}
__device__ __forceinline__ float bf2f(u16 h) {
    return __uint_as_float(((unsigned)h) << 16);
}

// ------------------------------------------------------------------
// patchify: img (B,3,224,224) -> patches (PROWS, 768)
// ------------------------------------------------------------------
__global__ __launch_bounds__(256) void patchify_k(const float* __restrict__ img,
                                                  float* __restrict__ out) {
    int idx = blockIdx.x * 256 + threadIdx.x;
    if (idx >= PROWS * PATCH_K) return;
    int r = idx / PATCH_K, col = idx - r * PATCH_K;
    int b = r / NPATCH, p = r - b * NPATCH;
    int ph = p / 14, pw = p - ph * 14;
    int c = col >> 8, rem = col & 255, py = rem >> 4, px = rem & 15;
    out[idx] = img[((b * C_IN + c) * IMG_SZ + ph * P_SZ + py) * IMG_SZ + pw * P_SZ + px];
}

// ------------------------------------------------------------------
// assemble x = concat(cls, xemb) + pos   -> (B, MSEQ, DDIM)
// ------------------------------------------------------------------
__global__ __launch_bounds__(256) void assemble_k(const float* __restrict__ xemb,
                                                  const float* __restrict__ cls,
                                                  const float* __restrict__ pos,
                                                  float* __restrict__ x) {
    int idx = blockIdx.x * 256 + threadIdx.x;
    if (idx >= ROWS * DDIM) return;
    int d = idx % DDIM;
    int bm = idx / DDIM;
    int m = bm % MSEQ, b = bm / MSEQ;
    float v;
    if (m == 0) v = cls[d];
    else        v = xemb[((b * NPATCH) + (m - 1)) * DDIM + d];
    x[idx] = v + pos[m * DDIM + d];
}

// ------------------------------------------------------------------
// layernorm over last dim (DDIM=192), one wave per row
// ------------------------------------------------------------------
__global__ __launch_bounds__(256) void layernorm_k(const float* __restrict__ x,
                                                   const float* __restrict__ g,
                                                   const float* __restrict__ b,
                                                   float* __restrict__ o, int nrows) {
    int wave = threadIdx.x >> 6;
    int lane = threadIdx.x & 63;
    int row = blockIdx.x * 4 + wave;
    if (row >= nrows) return;
    const float* xr = x + (long)row * DDIM;
    float v0 = xr[lane], v1 = xr[lane + 64], v2 = xr[lane + 128];
    float s = v0 + v1 + v2;
    #pragma unroll
    for (int off = 1; off < 64; off <<= 1) s += __shfl_xor(s, off);
    float mu = s * (1.f / 192.f);
    float d0 = v0 - mu, d1 = v1 - mu, d2 = v2 - mu;
    float q = d0 * d0 + d1 * d1 + d2 * d2;
    #pragma unroll
    for (int off = 1; off < 64; off <<= 1) q += __shfl_xor(q, off);
    float inv = rsqrtf(q * (1.f / 192.f) + 1e-5f);
    float* orow = o + (long)row * DDIM;
    orow[lane]       = d0 * inv * g[lane]       + b[lane];
    orow[lane + 64]  = d1 * inv * g[lane + 64]  + b[lane + 64];
    orow[lane + 128] = d2 * inv * g[lane + 128] + b[lane + 128];
}

// ------------------------------------------------------------------
// convA: split xf/xb into 3 exact bf16 planes in MFMA FRAGMENT ORDER
// [3][MFRAGS][KBLKS][lane*8]: frag element j of lane l is
// A[row = mf*32 + (l&31)][k = kb*16 + (l>>5)*8 + j].
// A wave's frag read in the GEMM = 1KB contiguous. Pad rows -> 0.
// ------------------------------------------------------------------
__global__ __launch_bounds__(256) void convA_k(const float* __restrict__ xf,
                                               const float* __restrict__ xb,
                                               u16* __restrict__ Af3,
                                               u16* __restrict__ Ab3) {
    int idx = blockIdx.x * 256 + threadIdx.x;      // MFRAGS*KBLKS*64
    if (idx >= MFRAGS * KBLKS * 64) return;
    int lane = idx & 63;
    int kb = (idx >> 6) % KBLKS;
    int mf = idx / (64 * KBLKS);
    int row = mf * 32 + (lane & 31);
    int k = kb * 16 + (lane >> 5) * 8;
    long fo = ((long)mf * KBLKS + kb) * FRAG + (long)lane * 8;
    const long plane = (long)MFRAGS * KBLKS * FRAG;
    #pragma unroll
    for (int s = 0; s < 2; ++s) {
        const float* src = s ? xb : xf;
        u16* out = s ? Ab3 : Af3;
        uint4 hq = {0,0,0,0}, mq = {0,0,0,0}, lq = {0,0,0,0};
        if (row < ROWS) {
            u16* hp = (u16*)&hq; u16* mp = (u16*)&mq; u16* lp = (u16*)&lq;
            const float* xr = src + (long)row * EDIM + k;
            #pragma unroll
            for (int j = 0; j < 8; ++j) {
                float x = xr[j];
                u16 hb = f2bf(x);        float fh = bf2f(hb);
                float r1 = x - fh;
                u16 mb = f2bf(r1);       float fm = bf2f(mb);
                u16 lb = f2bf(r1 - fm);
                hp[j] = hb; mp[j] = mb; lp[j] = lb;
            }
        }
        *(uint4*)&out[fo] = hq;
        *(uint4*)&out[plane + fo] = mq;
        *(uint4*)&out[2 * plane + fo] = lq;
    }
}

// ------------------------------------------------------------------
// convWt: W (K=384 x N=6144 fp32) -> 3 bf16 planes in FRAGMENT ORDER
// [3][NFRAGS][KBLKS][lane*8]: element j of lane l is
// W[k = kb*16 + (l>>5)*8 + j][n = nf*32 + (l&31)].
// 64x64 LDS transpose; z in {0..3} selects {WBf,WCf,WBb,WCb}.
// ------------------------------------------------------------------
__global__ __launch_bounds__(256) void convWt_k(const float* __restrict__ W0,
                                                const float* __restrict__ W1,
                                                const float* __restrict__ W2,
                                                const float* __restrict__ W3,
                                                u16* __restrict__ Wt) {
    int z = blockIdx.z;
    const float* W = (z == 0) ? W0 : (z == 1) ? W1 : (z == 2) ? W2 : W3;
    const long plane = (long)NFRAGS * KBLKS * FRAG;
    u16* out = Wt + (long)z * 3L * plane;
    __shared__ float tile[64][65];
    int n0 = blockIdx.x * 64, k0 = blockIdx.y * 64;
    int t = threadIdx.x;
    #pragma unroll
    for (int i = 0; i < 16; ++i) {
        int id = t + 256 * i;
        int kk = id >> 6, nn = id & 63;
        tile[kk][nn] = W[(long)(k0 + kk) * ENDIM + n0 + nn];
    }
    __syncthreads();
    #pragma unroll
    for (int i = 0; i < 2; ++i) {
        int id = t + 256 * i;
        int nn = id >> 3, ch = id & 7;       // ch: k-chunk of 8 within the 64
        int n = n0 + nn;
        int kc = k0 + ch * 8;
        int nf = n >> 5, l31 = n & 31;
        int kb = kc >> 4, l5 = (kc >> 3) & 1;
        uint4 hq, mq, lq;
        u16* hp = (u16*)&hq; u16* mp = (u16*)&mq; u16* lp = (u16*)&lq;
        #pragma unroll
        for (int j = 0; j < 8; ++j) {
            float x = tile[ch * 8 + j][nn];
            u16 hb = f2bf(x);        float fh = bf2f(hb);
            float r1 = x - fh;
            u16 mb = f2bf(r1);       float fm = bf2f(mb);
            u16 lb = f2bf(r1 - fm);
            hp[j] = hb; mp[j] = mb; lp[j] = lb;
        }
        long fo = ((long)nf * KBLKS + kb) * FRAG + (long)(l5 * 32 + l31) * 8;
        *(uint4*)&out[fo] = hq;
        *(uint4*)&out[plane + fo] = mq;
        *(uint4*)&out[2 * plane + fo] = lq;
    }
}

// ------------------------------------------------------------------
// MFMA GEMM, 6-term bf16x3-split, NO LDS / NO BARRIERS: both operands
// pre-swizzled to fragment order, so every frag load is one coalesced
// 1KB global read (L2-resident). Latency hidden by wave overlap +
// compiler pipelining — no barrier drain. Tile 128x128, 4 waves
// (2x2 of 64x64), v_mfma_f32_32x32x16_bf16, k-ascending order.
// C/D layout col=lane&31,row=(reg&3)+8*(reg>>2)+4*(lane>>5) [r13-
// verified end-to-end]. gridDim.z=2 shares A across the {B,C} pair.
// ------------------------------------------------------------------
__global__ __launch_bounds__(256) void gemm_mfma(
        const u16* __restrict__ A3,                      // [3][MFRAGS][KBLKS][FRAG]
        const u16* __restrict__ Wt0, const float* __restrict__ b0, float* __restrict__ C0,
        const u16* __restrict__ Wt1, const float* __restrict__ b1, float* __restrict__ C1) {
    const u16* Wt     = blockIdx.z ? Wt1 : Wt0;          // [3][NFRAGS][KBLKS][FRAG]
    const float* bias = blockIdx.z ? b1 : b0;
    float* C          = blockIdx.z ? C1 : C0;
    int t = threadIdx.x;
    int lane = t & 63, wv = t >> 6;
    int wr = wv >> 1, wc = wv & 1;
    int l31 = lane & 31, l5 = lane >> 5;
    int mf0 = blockIdx.y * 4 + wr * 2;
    int nf0 = blockIdx.x * 4 + wc * 2;
    const u16* Ab = A3 + (long)lane * 8;
    const u16* Wb = Wt + (long)lane * 8;
    f32x16 acc[2][2] = {};

    for (int kb = 0; kb < KBLKS; ++kb) {
        bf16x8 af[2][3], wf[2][3];
        #pragma unroll
        for (int r = 0; r < 2; ++r)
            #pragma unroll
            for (int p = 0; p < 3; ++p)
                af[r][p] = *(const bf16x8*)(Ab + (((long)p * MFRAGS + mf0 + r) * KBLKS + kb) * FRAG);
        #pragma unroll
        for (int c = 0; c < 2; ++c)
            #pragma unroll
            for (int p = 0; p < 3; ++p)
                wf[c][p] = *(const bf16x8*)(Wb + (((long)p * NFRAGS + nf0 + c) * KBLKS + kb) * FRAG);
        #pragma unroll
        for (int r = 0; r < 2; ++r)
            #pragma unroll
            for (int c = 0; c < 2; ++c) {
                f32x16 d = acc[r][c];
                d = __builtin_amdgcn_mfma_f32_32x32x16_bf16(af[r][0], wf[c][0], d, 0, 0, 0);
                d = __builtin_amdgcn_mfma_f32_32x32x16_bf16(af[r][0], wf[c][1], d, 0, 0, 0);
                d = __builtin_amdgcn_mfma_f32_32x32x16_bf16(af[r][1], wf[c][0], d, 0, 0, 0);
                d = __builtin_amdgcn_mfma_f32_32x32x16_bf16(af[r][0], wf[c][2], d, 0, 0, 0);
                d = __builtin_amdgcn_mfma_f32_32x32x16_bf16(af[r][2], wf[c][0], d, 0, 0, 0);
                d = __builtin_amdgcn_mfma_f32_32x32x16_bf16(af[r][1], wf[c][1], d, 0, 0, 0);
                acc[r][c] = d;
            }
    }
    int rowBase = blockIdx.y * 128;
    long colBase = (long)blockIdx.x * 128;
    #pragma unroll
    for (int r = 0; r < 2; ++r) {
        int rb = rowBase + wr * 64 + r * 32 + 4 * l5;
        #pragma unroll
        for (int c = 0; c < 2; ++c) {
            long cb = colBase + wc * 64 + c * 32 + l31;
            float bv = bias[cb];
            #pragma unroll
            for (int i = 0; i < 16; ++i) {
                int rr = rb + (i & 3) + 8 * (i >> 2);
                if (rr < ROWS) C[(long)rr * ENDIM + cb] = acc[r][c][i] + bv;
            }
        }
    }
}

// ------------------------------------------------------------------
// SMALL fp32 GEMM: one WAVE per 32x32 tile, 4x4/thread, double-
// buffered LDS. gridDim.z selects two independent sets (Wx+Wz, Df+Db).
// SP = correctly-rounded softplus epilogue. k-ascending FMA order
// (Delta path must stay bit-exact: P-trajectory depends on it).
// ------------------------------------------------------------------
#define SBK 16
template<bool SP, bool HASB2, bool HASRES>
__global__ __launch_bounds__(64) void gemm_s(const float* __restrict__ A0,
                                             const float* __restrict__ W0,
                                             const float* __restrict__ b10,
                                             const float* __restrict__ b20,
                                             const float* __restrict__ r0,
                                             float* __restrict__ C0,
                                             const float* __restrict__ A1,
                                             const float* __restrict__ W1,
                                             const float* __restrict__ b11,
                                             const float* __restrict__ b21,
                                             const float* __restrict__ r1,
                                             float* __restrict__ C1,
                                             int M, int N, int K) {
    const float* A  = blockIdx.z ? A1  : A0;
    const float* W  = blockIdx.z ? W1  : W0;
    const float* bp = blockIdx.z ? b11 : b10;
    const float* b2 = blockIdx.z ? b21 : b20;
    const float* rp = blockIdx.z ? r1  : r0;
    float*       C  = blockIdx.z ? C1  : C0;
    __shared__ float As[2][SBK][36];
    __shared__ float Wsh[2][SBK][36];
    int t = threadIdx.x;            // 0..63
    int tx = t & 7, ty = t >> 3;
    int rowBase = blockIdx.y * 32;
    long colBase = (long)blockIdx.x * 32;
    int rA = t >> 2, kqA = (t & 3) << 2;
    int kW = t >> 3, nqW = (t & 7) << 2;
    float acc[4][4] = {};
    int r0i = rowBase + rA, r1i = r0i + 16;

    auto loadA = [&](int k0, float4& a0, float4& a1) {
        a0 = make_float4(0.f,0.f,0.f,0.f); a1 = a0;
        if (r0i < M) a0 = *(const float4*)&A[(long)r0i * K + k0 + kqA];
        if (r1i < M) a1 = *(const float4*)&A[(long)r1i * K + k0 + kqA];
    };
    auto stage = [&](int buf, float4 a0, float4 a1, float4 w0, float4 w1) {
        As[buf][kqA + 0][rA] = a0.x; As[buf][kqA + 1][rA] = a0.y;
        As[buf][kqA + 2][rA] = a0.z; As[buf][kqA + 3][rA] = a0.w;
        As[buf][kqA + 0][rA + 16] = a1.x; As[buf][kqA + 1][rA + 16] = a1.y;
        As[buf][kqA + 2][rA + 16] = a1.z; As[buf][kqA + 3][rA + 16] = a1.w;
        *(float4*)&Wsh[buf][kW][nqW]     = w0;
        *(float4*)&Wsh[buf][kW + 8][nqW] = w1;
    };
    auto compute = [&](int buf) {
        #pragma unroll
        for (int kk = 0; kk < SBK; ++kk) {
            float4 av = *(const float4*)&As[buf][kk][ty << 2];
            float4 wv = *(const float4*)&Wsh[buf][kk][tx << 2];
            float ar[4] = {av.x, av.y, av.z, av.w};
            float wr[4] = {wv.x, wv.y, wv.z, wv.w};
            #pragma unroll
            for (int i = 0; i < 4; ++i)
                #pragma unroll
                for (int j = 0; j < 4; ++j) acc[i][j] += ar[i] * wr[j];
        }
    };

    {
        float4 a0, a1;
        loadA(0, a0, a1);
        float4 w0 = *(const float4*)&W[(long)kW * N + colBase + nqW];
        float4 w1 = *(const float4*)&W[(long)(kW + 8) * N + colBase + nqW];
        stage(0, a0, a1, w0, w1);
    }
    __syncthreads();
    int cur = 0;
    int nt = K / SBK;
    for (int kt = 1; kt < nt; ++kt) {
        int k0 = kt * SBK;
        float4 a0, a1;
        loadA(k0, a0, a1);
        float4 w0 = *(const float4*)&W[(long)(k0 + kW) * N + colBase + nqW];
        float4 w1 = *(const float4*)&W[(long)(k0 + kW + 8) * N + colBase + nqW];
        compute(cur);
        stage(cur ^ 1, a0, a1, w0, w1);
        __syncthreads();
        cur ^= 1;
    }
    compute(cur);

    #pragma unroll
    for (int i = 0; i < 4; ++i) {
        int r = rowBase + (ty << 2) + i;
        if (r >= M) break;
        long cb = colBase + (tx << 2);
        float vv[4];
        #pragma unroll
        for (int j = 0; j < 4; ++j) {
            float v = acc[i][j] + bp[cb + j];
            if (HASB2) v += b2[cb + j];
            if (SP) {  // correctly-rounded fp32 softplus via fp64
                double vd = (double)v;
                v = (float)(log1p(exp(-fabs(vd))) + fmax(vd, 0.0));
            }
            if (HASRES) v += rp[(long)r * N + cb + j];
            vv[j] = v;
        }
        float4 o; o.x = vv[0]; o.y = vv[1]; o.z = vv[2]; o.w = vv[3];
        *(float4*)&C[(long)r * N + cb] = o;
    }
}

// ------------------------------------------------------------------
// fused depthwise conv (fwd + bwd) + SiLU
// ------------------------------------------------------------------
__global__ __launch_bounds__(256) void dwconv_k(const float* __restrict__ xp,
                                                const float* __restrict__ wf,
                                                const float* __restrict__ bf,
                                                const float* __restrict__ wb,
                                                const float* __restrict__ bb,
                                                float* __restrict__ xf,
                                                float* __restrict__ xb) {
    int idx = blockIdx.x * 256 + threadIdx.x;
    if (idx >= ROWS * EDIM) return;
    int e = idx % EDIM;
    int bm = idx / EDIM;
    int m = bm % MSEQ, b = bm / MSEQ;
    const float* base = xp + (long)b * MSEQ * EDIM + e;
    float xm1 = (m > 0)        ? base[(m - 1) * EDIM] : 0.f;
    float x0  =                  base[m * EDIM];
    float xp1 = (m < MSEQ - 1) ? base[(m + 1) * EDIM] : 0.f;
    float f = wf[e * 3 + 0] * xm1 + wf[e * 3 + 1] * x0 + wf[e * 3 + 2] * xp1 + bf[e];
    float r = wb[e * 3 + 0] * xp1 + wb[e * 3 + 1] * x0 + wb[e * 3 + 2] * xm1 + bb[e];
    xf[idx] = silu_f(f);
    xb[idx] = silu_f(r);
}

// ------------------------------------------------------------------
// SSM recurrence, PHASE-PARALLEL, bit-exact fp32 chains; CR fp64
// transcendentals. One block per (b,e). ycomb!=nullptr fuses combine.
// ------------------------------------------------------------------
__global__ __launch_bounds__(256) void ssm_scan_k(const float* __restrict__ Bm,
                                                  const float* __restrict__ Cm,
                                                  const float* __restrict__ Dlt,
                                                  const float* __restrict__ xs,
                                                  const float* __restrict__ Apar,
                                                  float* __restrict__ y,
                                                  const float* __restrict__ yother,
                                                  const float* __restrict__ zg,
                                                  float* __restrict__ ycomb) {
#pragma clang fp contract(off)
    __shared__ float lgP[MSEQ][17];
    __shared__ float trm[MSEQ][17];
    __shared__ signed char sgn[MSEQ][17];
    int be = blockIdx.x;
    int b = be / EDIM, e = be - b * EDIM;
    int t = threadIdx.x;
    int n0 = t & 15;
    float Ap = Apar[e * NSTATE + n0];
    const long dxBase = (long)b * MSEQ * EDIM + e;
    const long bcBase = (long)b * MSEQ * ENDIM + e * NSTATE;

    for (int idx = t; idx < MSEQ * NSTATE; idx += 256) {
        int m = idx >> 4;
        float delta = Dlt[dxBase + (long)m * EDIM];
        float A = delta * Ap;
        float sa = (A > 0.f) ? 1.f : ((A < 0.f) ? -1.f : 0.f);
        float absA = fmaxf(fabsf(A), 1e-6f);
        lgP[m][n0] = (float)log((double)absA);
        sgn[m][n0] = (signed char)sa;
    }
    __syncthreads();
    if (t < NSTATE) {
        float cl = 0.f, cs = 1.f;
        for (int m = 0; m < MSEQ; ++m) {
            float sa = (float)sgn[m][t];
            cs = cs * sa;
            cl = cl + lgP[m][t];
            lgP[m][t] = cl;
            sgn[m][t] = (signed char)cs;
        }
    }
    __syncthreads();
    for (int idx = t; idx < MSEQ * NSTATE; idx += 256) {
        int m = idx >> 4;
        float cl = lgP[m][n0];
        float cs = (float)sgn[m][n0];
        float ex = (float)exp((double)cl);
        float P = cs * ex;
        float tt = P + 1e-6f;
        float invP = 1.0f / tt;
        float delta = Dlt[dxBase + (long)m * EDIM];
        float xv = xs[dxBase + (long)m * EDIM];
        float Bv = Bm[bcBase + (long)m * ENDIM + n0];
        float Bfull = delta * Bv;
        float t1 = invP * Bfull;
        float t2 = t1 * xv;
        trm[m][n0] = t2;
        lgP[m][n0] = P;
    }
    __syncthreads();
    if (t < NSTATE) {
        float S = 0.f;
        for (int m = 0; m < MSEQ; ++m) {
            S = S + trm[m][t];
            float h = lgP[m][t] * S;
            trm[m][t] = h;
        }
    }
    __syncthreads();
    for (int m = t; m < MSEQ; m += 256) {
        const float* cp = &Cm[bcBase + (long)m * ENDIM];
        float a[16];
        #pragma unroll
        for (int n = 0; n < 16; ++n) a[n] = trm[m][n] * cp[n];
        float b0 = a[0] + a[8],  b1 = a[1] + a[9];
        float b2v = a[2] + a[10], b3 = a[3] + a[11];
        float b4 = a[4] + a[12], b5 = a[5] + a[13];
        float b6 = a[6] + a[14], b7 = a[7] + a[15];
        float c0 = b0 + b1, c2 = b2v + b3, c4 = b4 + b5, c6 = b6 + b7;
        float d0 = c0 + c2, d4 = c4 + c6;
        float val = d0 + d4;
        long o = dxBase + (long)m * EDIM;
        if (ycomb) ycomb[o] = (yother[o] + val) * silu_f(zg[o]);
        else       y[o] = val;
    }
}

extern "C" void kernel_launch(void* const* d_in, const int* in_sizes, int n_in,
                              void* d_out, int out_size, void* d_ws, size_t ws_size,
                              hipStream_t stream) {
    const float* img     = (const float*)d_in[0];
    const float* patch_w = (const float*)d_in[1];
    const float* patch_b = (const float*)d_in[2];
    const float* cls     = (const float*)d_in[3];
    const float* pos     = (const float*)d_in[4];
    const float* ln_g    = (const float*)d_in[5];
    const float* ln_b    = (const float*)d_in[6];
    const float* Wx  = (const float*)d_in[7];  const float* bx  = (const float*)d_in[8];
    const float* Wz  = (const float*)d_in[9];  const float* bz  = (const float*)d_in[10];
    const float* cwf = (const float*)d_in[11]; const float* cbf = (const float*)d_in[12];
    const float* cwb = (const float*)d_in[13]; const float* cbb = (const float*)d_in[14];
    const float* WBf = (const float*)d_in[15]; const float* bBf = (const float*)d_in[16];
    const float* WCf = (const float*)d_in[17]; const float* bCf = (const float*)d_in[18];
    const float* WDf = (const float*)d_in[19]; const float* bDf = (const float*)d_in[20];
    const float* Af  = (const float*)d_in[21]; const float* dbf = (const float*)d_in[22];
    const float* WBb = (const float*)d_in[23]; const float* bBb = (const float*)d_in[24];
    const float* WCb = (const float*)d_in[25]; const float* bCb = (const float*)d_in[26];
    const float* WDb = (const float*)d_in[27]; const float* bDb = (const float*)d_in[28];
    const float* Ab  = (const float*)d_in[29]; const float* dbb = (const float*)d_in[30];
    const float* Wout= (const float*)d_in[31]; const float* bout= (const float*)d_in[32];
    const float* ng  = (const float*)d_in[33]; const float* nb  = (const float*)d_in[34];

    float* ws = (float*)d_ws;
    float* xA   = ws;
    float* xB   = xA  + (size_t)ROWS * DDIM;
    float* xn   = xB  + (size_t)ROWS * DDIM;
    float* xp   = xn  + (size_t)ROWS * DDIM;
    float* zb   = xp  + (size_t)ROWS * EDIM;
    float* xfb  = zb  + (size_t)ROWS * EDIM;
    float* xbb  = xfb + (size_t)ROWS * EDIM;
    float* yfb  = xbb + (size_t)ROWS * EDIM;
    float* ybb  = yfb + (size_t)ROWS * EDIM;
    float* ycb  = ybb + (size_t)ROWS * EDIM;
    float* dlt  = ycb + (size_t)ROWS * EDIM;
    float* dlt2 = dlt + (size_t)ROWS * EDIM;
    float* Bmb  = dlt2 + (size_t)ROWS * EDIM;         // ROWS*ENDIM
    float* Cmb  = Bmb + (size_t)ROWS * ENDIM;
    u16*   Af3  = (u16*)(Cmb + (size_t)ROWS * ENDIM); // [3][MFRAGS][KBLKS][FRAG]
    u16*   Ab3  = Af3 + 3L * MFRAGS * KBLKS * FRAG;
    u16*   Wt4  = Ab3 + 3L * MFRAGS * KBLKS * FRAG;   // [4][3][NFRAGS][KBLKS][FRAG]
    // patchify scratch aliases the (not-yet-needed) B buffer
    float* patches = Bmb;                             // PROWS*PATCH_K
    float* xemb    = Bmb + (size_t)PROWS * PATCH_K;   // PROWS*DDIM

    const long WtSz = 3L * NFRAGS * KBLKS * FRAG;     // u16 per converted matrix

    // --- patch embedding ---
    patchify_k<<<(PROWS * PATCH_K + 255) / 256, 256, 0, stream>>>(img, patches);
    {   // 1568x192x768 GEMM
        dim3 g(DDIM / 32, (PROWS + 31) / 32, 1);
        gemm_s<false, false, false><<<g, 64, 0, stream>>>(
            patches, patch_w, patch_b, nullptr, nullptr, xemb,
            patches, patch_w, patch_b, nullptr, nullptr, xemb,
            PROWS, DDIM, PATCH_K);
    }
    assemble_k<<<(ROWS * DDIM + 255) / 256, 256, 0, stream>>>(xemb, cls, pos, xA);

    float* cur = xA; float* nxt = xB;
    for (int i = 0; i < LLAYERS; ++i) {
        layernorm_k<<<(ROWS + 3) / 4, 256, 0, stream>>>(cur, ln_g + i * DDIM, ln_b + i * DDIM, xn, ROWS);
        {   // Wx + Wz fused (shared A=xn)
            dim3 g(EDIM / 32, (ROWS + 31) / 32, 2);
            gemm_s<false, false, false><<<g, 64, 0, stream>>>(
                xn, Wx + (size_t)i * DDIM * EDIM, bx + i * EDIM, nullptr, nullptr, xp,
                xn, Wz + (size_t)i * DDIM * EDIM, bz + i * EDIM, nullptr, nullptr, zb,
                ROWS, EDIM, DDIM);
        }
        dwconv_k<<<(ROWS * EDIM + 255) / 256, 256, 0, stream>>>(xp, cwf + i * EDIM * 3, cbf + i * EDIM,
                                                                cwb + i * EDIM * 3, cbb + i * EDIM, xfb, xbb);
        convA_k<<<(MFRAGS * KBLKS * 64 + 255) / 256, 256, 0, stream>>>(xfb, xbb, Af3, Ab3);
        {   // Df + Db fused (CR softplus epilogue) — fp32 path, P stays bit-exact
            dim3 g(EDIM / 32, (ROWS + 31) / 32, 2);
            gemm_s<true, true, false><<<g, 64, 0, stream>>>(
                xfb, WDf + (size_t)i * EDIM * EDIM, bDf + i * EDIM, dbf + i * EDIM, nullptr, dlt,
                xbb, WDb + (size_t)i * EDIM * EDIM, bDb + i * EDIM, dbb + i * EDIM, nullptr, dlt2,
                ROWS, EDIM, EDIM);
        }
        {   // convert the 4 big weight matrices -> fragment-ordered bf16x3 planes
            dim3 g(ENDIM / 64, EDIM / 64, 4);
            convWt_k<<<g, 256, 0, stream>>>(
                WBf + (size_t)i * EDIM * ENDIM, WCf + (size_t)i * EDIM * ENDIM,
                WBb + (size_t)i * EDIM * ENDIM, WCb + (size_t)i * EDIM * ENDIM, Wt4);
        }
        {   // Bf + Cf via MFMA (shared A planes)
            dim3 g(ENDIM / 128, AP_ROWS / 128, 2);
            gemm_mfma<<<g, 256, 0, stream>>>(
                Af3,
                Wt4 + 0 * WtSz, bBf + i * ENDIM, Bmb,
                Wt4 + 1 * WtSz, bCf + i * ENDIM, Cmb);
        }
        ssm_scan_k<<<BATCH * EDIM, 256, 0, stream>>>(Bmb, Cmb, dlt, xfb, Af + i * EDIM * NSTATE,
                                                     yfb, nullptr, nullptr, nullptr);
        {   // Bb + Cb via MFMA
            dim3 g(ENDIM / 128, AP_ROWS / 128, 2);
            gemm_mfma<<<g, 256, 0, stream>>>(
                Ab3,
                Wt4 + 2 * WtSz, bBb + i * ENDIM, Bmb,
                Wt4 + 3 * WtSz, bCb + i * ENDIM, Cmb);
        }
        // bwd scan with FUSED combine: ycb = (yfb + y_b) * silu(zb)
        ssm_scan_k<<<BATCH * EDIM, 256, 0, stream>>>(Bmb, Cmb, dlt2, xbb, Ab + i * EDIM * NSTATE,
                                                     ybb, yfb, zb, ycb);
        {   // Wout with residual
            dim3 g(DDIM / 32, (ROWS + 31) / 32, 1);
            gemm_s<false, false, true><<<g, 64, 0, stream>>>(
                ycb, Wout + (size_t)i * EDIM * DDIM, bout + i * DDIM, nullptr, cur, nxt,
                ycb, Wout + (size_t)i * EDIM * DDIM, bout + i * DDIM, nullptr, cur, nxt,
                ROWS, DDIM, EDIM);
        }
        float* t = cur; cur = nxt; nxt = t;
    }
    layernorm_k<<<(ROWS + 3) / 4, 256, 0, stream>>>(cur, ng, nb, (float*)d_out, ROWS);
}